// Round 10
// baseline (1030.784 us; speedup 1.0000x reference)
//
#include <hip/hip_runtime.h>
#include <math.h>

#define T_ 2048
#define H_ 2048
#define NH_ 16
#define NKV_ 8
#define D_ 128
#define E_ 16
#define I_ 1024
#define SI_ 1024

typedef _Float16 half8 __attribute__((ext_vector_type(8)));
typedef _Float16 half4_t __attribute__((ext_vector_type(4)));
typedef float f32x4 __attribute__((ext_vector_type(4)));

#define MFMA32(a,b,c) __builtin_amdgcn_mfma_f32_16x16x32_f16((a),(b),(c),0,0,0)

__device__ __constant__ float LO_S = 2048.0f;
__device__ __constant__ float LO_I = 1.0f/2048.0f;
#define EPS_ 1e-5f

#define GL16(gp, lp) __builtin_amdgcn_global_load_lds( \
    (const __attribute__((address_space(1))) unsigned int*)(const void*)(gp), \
    (__attribute__((address_space(3))) unsigned int*)(void*)(lp), 16, 0, 0)

// ---------------- RoPE tables (fp64 for bit-faithful inv_freq) ----------------
__global__ void tables_k(const int* __restrict__ pos, float* __restrict__ cosT, float* __restrict__ sinT) {
  int t = blockIdx.x;
  int j = threadIdx.x; // 0..63
  float pf = (float)pow(10000.0, (double)j / 64.0);
  float invf = 1.0f / pf;
  float ang = (float)pos[t] * invf;
  cosT[t*64 + j] = (float)cos((double)ang);
  sinT[t*64 + j] = (float)sin((double)ang);
}

// ---------------- RMSNorm -> fp16 hi/lo pair ----------------
__global__ __launch_bounds__(256) void rmsnorm_k(const float* __restrict__ x, const float* __restrict__ w,
                                                 _Float16* __restrict__ oh, _Float16* __restrict__ ol) {
  int row = blockIdx.x;
  const float* xr = x + (size_t)row * H_;
  int tid = threadIdx.x;
  float4 a = *(const float4*)(xr + tid*8);
  float4 b = *(const float4*)(xr + tid*8 + 4);
  float ss = a.x*a.x + a.y*a.y + a.z*a.z + a.w*a.w + b.x*b.x + b.y*b.y + b.z*b.z + b.w*b.w;
  #pragma unroll
  for (int m = 1; m < 64; m <<= 1) ss += __shfl_xor(ss, m);
  __shared__ float wsum[4];
  int wid = tid >> 6, lane = tid & 63;
  if (lane == 0) wsum[wid] = ss;
  __syncthreads();
  float tot = wsum[0] + wsum[1] + wsum[2] + wsum[3];
  float rinv = 1.0f / sqrtf(tot / (float)H_ + EPS_);
  const float* av = (const float*)&a;
  const float* bv = (const float*)&b;
  #pragma unroll
  for (int j = 0; j < 8; ++j) {
    float xv = (j < 4) ? av[j] : bv[j-4];
    float val = xv * rinv * w[tid*8 + j];
    _Float16 h = (_Float16)val;
    size_t o = (size_t)row*H_ + tid*8 + j;
    oh[o] = h;
    ol[o] = (_Float16)((val - (float)h) * LO_S);
  }
}

// ---------------- QKV postprocess: q/k rmsnorm + rope, v transpose; split fp16 ----------------
__global__ __launch_bounds__(128) void qkvpost_k(
    const float* __restrict__ qkv, const float* __restrict__ qnw, const float* __restrict__ knw,
    const float* __restrict__ cosT, const float* __restrict__ sinT,
    _Float16* __restrict__ qh, _Float16* __restrict__ ql,
    _Float16* __restrict__ kh, _Float16* __restrict__ kl,
    _Float16* __restrict__ vth, _Float16* __restrict__ vtl) {
  int t = blockIdx.x, u = blockIdx.y, d = threadIdx.x;
  float val = qkv[(size_t)t*4096 + u*128 + d];
  __shared__ float sv[128];
  __shared__ float ssum[2];
  if (u < 24) {
    float ss = val * val;
    #pragma unroll
    for (int m = 1; m < 64; m <<= 1) ss += __shfl_xor(ss, m);
    if ((d & 63) == 0) ssum[d >> 6] = ss;
    __syncthreads();
    float rinv = 1.0f / sqrtf((ssum[0] + ssum[1]) / 128.0f + EPS_);
    const float* nw = (u < 16) ? qnw : knw;
    float nv = val * rinv * nw[d];
    sv[d] = nv;
    __syncthreads();
    int j = d & 63;
    float c = cosT[t*64 + j], s = sinT[t*64 + j];
    float x1 = sv[j], x2 = sv[j + 64];
    float o = (d < 64) ? (x1*c - x2*s) : (x2*c + x1*s);
    _Float16 hv = (_Float16)o;
    _Float16 lv = (_Float16)((o - (float)hv) * LO_S);
    if (u < 16) { size_t off = ((size_t)u*T_ + t)*D_ + d; qh[off] = hv; ql[off] = lv; }
    else { size_t off = ((size_t)(u-16)*T_ + t)*D_ + d; kh[off] = hv; kl[off] = lv; }
  } else {
    int kv = u - 24;
    _Float16 hv = (_Float16)val;
    _Float16 lv = (_Float16)((val - (float)hv) * LO_S);
    size_t off = ((size_t)kv*D_ + d)*T_ + t;
    vth[off] = hv; vtl[off] = lv;
  }
}

// ---------------- weight transpose + fp16 convert (optional split) ----------------
template<bool SPL>
__global__ __launch_bounds__(256) void transpose_k(const float* __restrict__ in, _Float16* __restrict__ oh,
                                                   _Float16* __restrict__ ol, int R, int C) {
  size_t zo = (size_t)blockIdx.z * R * C;
  in += zo; oh += zo; if (SPL) ol += zo;
  __shared__ float tile[32][33];
  int c0 = blockIdx.x*32, r0 = blockIdx.y*32;
  int tid = threadIdx.x;
  int lr = tid >> 3;
  int lc = (tid & 7) * 4;
  float4 v = *(const float4*)(in + (size_t)(r0+lr)*C + c0 + lc);
  tile[lr][lc+0]=v.x; tile[lr][lc+1]=v.y; tile[lr][lc+2]=v.z; tile[lr][lc+3]=v.w;
  __syncthreads();
  half4_t hv, lv;
  #pragma unroll
  for (int j = 0; j < 4; ++j) {
    float f = tile[lc+j][lr];
    _Float16 h = (_Float16)f;
    hv[j] = h;
    if (SPL) lv[j] = (_Float16)((f - (float)h) * LO_S);
  }
  size_t ob = (size_t)(c0+lr)*R + r0 + lc;
  *(half4_t*)(oh + ob) = hv;
  if (SPL) *(half4_t*)(ol + ob) = lv;
}

// gate/up interleaving transpose: out[2j+p][h] = in[h][j + p*Ih]
__global__ __launch_bounds__(256) void transpose_gu_k(const float* __restrict__ in, _Float16* __restrict__ out,
                                                      int R, int Ih) {
  size_t zi = (size_t)blockIdx.z * R * 2 * Ih;
  in += zi; out += zi;
  __shared__ float tg[32][17], tu[32][17];
  int j0 = blockIdx.x*16, h0 = blockIdx.y*32;
  int tid = threadIdx.x;
  int lh = tid >> 3;
  int lj = (tid & 7) * 2;
  int C = 2*Ih;
  float2 g = *(const float2*)(in + (size_t)(h0+lh)*C + j0 + lj);
  float2 u = *(const float2*)(in + (size_t)(h0+lh)*C + Ih + j0 + lj);
  tg[lh][lj]=g.x; tg[lh][lj+1]=g.y; tu[lh][lj]=u.x; tu[lh][lj+1]=u.y;
  __syncthreads();
  int orow = tid >> 3;
  int oj = orow >> 1, op = orow & 1;
  int oc = (tid & 7) * 4;
  float (*sel)[17] = op ? tu : tg;
  half4_t pack;
  #pragma unroll
  for (int q = 0; q < 4; ++q) pack[q] = (_Float16)sel[oc+q][oj];
  *(half4_t*)(out + (size_t)(2*(j0+oj)+op)*R + h0 + oc) = pack;
}

// ---------------- flash attention: unpaired tiles (2 blocks/CU), dbuf LDS, 2-way V swizzle ----------------
__global__ __launch_bounds__(256) void attn_k(
    const _Float16* __restrict__ qh_, const _Float16* __restrict__ ql_,
    const _Float16* __restrict__ kh_, const _Float16* __restrict__ kl_,
    const _Float16* __restrict__ vh_, const _Float16* __restrict__ vl_,
    _Float16* __restrict__ aoh, _Float16* __restrict__ aol) {
  __shared__ _Float16 sK [2][4096];
  __shared__ _Float16 sKl[2][4096];
  __shared__ _Float16 sV [2][4096];
  __shared__ _Float16 sVl[2][4096];
  const int head = blockIdx.x;
  const int tile = 31 - blockIdx.y;       // heavy tiles dispatch first
  const int kvh = head >> 1;
  const int wid = threadIdx.x >> 6, lane = threadIdx.x & 63;
  const int fr = lane & 15, fs = lane >> 4;
  const float scale = 0.08838834764831845f;

  const char* kbC  = (const char*)(kh_ + (size_t)kvh*T_*D_);
  const char* kbCl = (const char*)(kl_ + (size_t)kvh*T_*D_);
  const char* vbC  = (const char*)(vh_ + (size_t)kvh*D_*T_);
  const char* vbCl = (const char*)(vl_ + (size_t)kvh*D_*T_);

  // K: row r (256B), 16B-unit u, source unit u^(r&7).
  // V^T: row d (64B), unit uv, source unit uv^((d>>2)&3)  [bits b2,b3 of d -> 2-way only]
  auto stage = [&](int buf, int kvt) {
    #pragma unroll
    for (int i = 0; i < 2; ++i) {
      const int off  = wid*2048 + i*1024;
      const int loff = off + lane*16;
      const int r  = loff >> 8;
      const int u  = (loff >> 4) & 15;
      const int us = u ^ (r & 7);
      const size_t gb = ((size_t)(kvt + r) << 8) + ((size_t)us << 4);
      GL16(kbC  + gb, (char*)&sK [buf][0] + off);
      GL16(kbCl + gb, (char*)&sKl[buf][0] + off);
      const int d   = loff >> 6;
      const int uv  = (loff >> 4) & 3;
      const int uvs = uv ^ ((d >> 2) & 3);
      const size_t gvb = (size_t)d*(T_*2) + (size_t)kvt*2 + ((size_t)uvs << 4);
      GL16(vbC  + gvb, (char*)&sV [buf][0] + off);
      GL16(vbCl + gvb, (char*)&sVl[buf][0] + off);
    }
  };

  const int q0 = tile*64 + wid*16;
  const int qrow = q0 + fr;
  const _Float16* qb_  = qh_ + ((size_t)head*T_ + qrow)*D_;
  const _Float16* qlb_ = ql_ + ((size_t)head*T_ + qrow)*D_;
  half8 qf[4], qfl[4];
  #pragma unroll
  for (int s = 0; s < 4; ++s) {
    qf[s]  = *(const half8*)(qb_  + s*32 + fs*8);
    qfl[s] = *(const half8*)(qlb_ + s*32 + fs*8);
  }
  float m = -1e30f, lsum = 0.f;
  f32x4 oacc[8] = {};
  f32x4 oacc2[8] = {};
  const int nc = 2*tile + 2;

  stage(0, 0);
  #pragma unroll 1
  for (int c = 0; c < nc; ++c) {
    const int kvt = c*32;
    const int buf = c & 1;
    __syncthreads();
    if (c + 1 < nc) stage(buf ^ 1, kvt + 32);

    f32x4 sa = {0,0,0,0}, sa2 = {0,0,0,0}, sb = {0,0,0,0}, sb2 = {0,0,0,0};
    __builtin_amdgcn_s_setprio(1);
    #pragma unroll
    for (int s = 0; s < 4; ++s) {
      const int rA = fr, rB = fr + 16;
      const int eA = (((4*s + fs) ^ (rA & 7)) << 3);
      const int eB = (((4*s + fs) ^ (rB & 7)) << 3);
      half8 kfA  = *(const half8*)&sK [buf][rA*128 + eA];
      half8 kflA = *(const half8*)&sKl[buf][rA*128 + eA];
      half8 kfB  = *(const half8*)&sK [buf][rB*128 + eB];
      half8 kflB = *(const half8*)&sKl[buf][rB*128 + eB];
      sa  = MFMA32(kfA, qf[s], sa);
      sa2 = MFMA32(kfA, qfl[s], sa2);
      sa2 = MFMA32(kflA, qf[s], sa2);
      sb  = MFMA32(kfB, qf[s], sb);
      sb2 = MFMA32(kfB, qfl[s], sb2);
      sb2 = MFMA32(kflB, qf[s], sb2);
    }
    __builtin_amdgcn_s_setprio(0);

    float sv[8];
    #pragma unroll
    for (int r = 0; r < 4; ++r) {
      float xA = (sa[r] + sa2[r]*LO_I) * scale;
      sv[r] = (kvt + fs*4 + r > qrow) ? -INFINITY : xA;
      float xB = (sb[r] + sb2[r]*LO_I) * scale;
      sv[4+r] = (kvt + 16 + fs*4 + r > qrow) ? -INFINITY : xB;
    }
    float tm = -INFINITY;
    #pragma unroll
    for (int j = 0; j < 8; ++j) tm = fmaxf(tm, sv[j]);
    tm = fmaxf(tm, __shfl_xor(tm, 16));
    tm = fmaxf(tm, __shfl_xor(tm, 32));
    float mnew = fmaxf(m, tm);
    float p[8]; float ps = 0.f;
    #pragma unroll
    for (int j = 0; j < 8; ++j) { p[j] = __expf(sv[j] - mnew); ps += p[j]; }
    ps += __shfl_xor(ps, 16);
    ps += __shfl_xor(ps, 32);
    if (mnew > m) {
      float f = __expf(m - mnew);
      lsum *= f;
      #pragma unroll
      for (int db = 0; db < 8; ++db) { oacc[db] *= f; oacc2[db] *= f; }
      m = mnew;
    }
    lsum += ps;
    half8 ph, pl;
    #pragma unroll
    for (int j = 0; j < 8; ++j) {
      _Float16 hp = (_Float16)p[j];
      ph[j] = hp;
      pl[j] = (_Float16)((p[j] - (float)hp) * LO_S);
    }

    __builtin_amdgcn_s_setprio(1);
    #pragma unroll
    for (int db = 0; db < 8; ++db) {
      const int d0 = db*16 + fr;
      const int base = d0*32;
      const int sw = (d0 >> 2) & 3;
      const int e1 = ((((fs>>1)    ) ^ sw) << 3) + (fs & 1)*4;
      const int e2 = (((2 + (fs>>1)) ^ sw) << 3) + (fs & 1)*4;
      half4_t v0  = *(const half4_t*)&sV [buf][base + e1];
      half4_t v1  = *(const half4_t*)&sV [buf][base + e2];
      half4_t v0l = *(const half4_t*)&sVl[buf][base + e1];
      half4_t v1l = *(const half4_t*)&sVl[buf][base + e2];
      half8 vf, vfl;
      #pragma unroll
      for (int j = 0; j < 4; ++j) { vf[j] = v0[j]; vf[4+j] = v1[j]; vfl[j] = v0l[j]; vfl[4+j] = v1l[j]; }
      oacc[db]  = MFMA32(vf, ph, oacc[db]);
      oacc2[db] = MFMA32(vf, pl, oacc2[db]);
      oacc2[db] = MFMA32(vfl, ph, oacc2[db]);
    }
    __builtin_amdgcn_s_setprio(0);
  }

  float inv = 1.0f / lsum;
  #pragma unroll
  for (int db = 0; db < 8; ++db) {
    #pragma unroll
    for (int r = 0; r < 4; ++r) {
      float val = (oacc[db][r] + oacc2[db][r]*LO_I) * inv;
      int dd = db*16 + fs*4 + r;
      size_t off = (size_t)qrow*(NH_*D_) + head*D_ + dd;
      _Float16 hv = (_Float16)val;
      aoh[off] = hv;
      aol[off] = (_Float16)((val - (float)hv) * LO_S);
    }
  }
}

// ---------------- router: fp32 logits, sigmoid, top-4, dispatch lists ----------------
__global__ __launch_bounds__(256) void router_k(const _Float16* __restrict__ x2h, const _Float16* __restrict__ x2l,
    const float* __restrict__ gw, const float* __restrict__ eb,
    int* __restrict__ cnt, int* __restrict__ list, float* __restrict__ wl) {
  int t = blockIdx.x*4 + (threadIdx.x >> 6);
  int lane = threadIdx.x & 63;
  const _Float16* xh = x2h + (size_t)t*H_;
  const _Float16* xl = x2l + (size_t)t*H_;
  f32x4 a0 = {0,0,0,0}, a1 = {0,0,0,0}, a2 = {0,0,0,0}, a3 = {0,0,0,0};
  for (int h = lane; h < H_; h += 64) {
    float xv = (float)xh[h] + (float)xl[h] * LO_I;
    const float* g = gw + (size_t)h*16;
    a0 += xv * (*(const f32x4*)(g));
    a1 += xv * (*(const f32x4*)(g+4));
    a2 += xv * (*(const f32x4*)(g+8));
    a3 += xv * (*(const f32x4*)(g+12));
  }
  float acc[16];
  #pragma unroll
  for (int j = 0; j < 4; ++j) { acc[j]=a0[j]; acc[4+j]=a1[j]; acc[8+j]=a2[j]; acc[12+j]=a3[j]; }
  #pragma unroll
  for (int mm = 1; mm < 64; mm <<= 1) {
    #pragma unroll
    for (int e2 = 0; e2 < 16; ++e2) acc[e2] += __shfl_xor(acc[e2], mm);
  }
  if (lane == 0) {
    float sig[16], biased[16];
    #pragma unroll
    for (int e2 = 0; e2 < 16; ++e2) {
      float s = 1.0f / (1.0f + expf(-acc[e2]));
      sig[e2] = s; biased[e2] = s + eb[e2];
    }
    int sel[4]; float wv[4]; float wsum = 0.f;
    unsigned used = 0;
    for (int j = 0; j < 4; ++j) {
      int bi = -1; float bv = -1e30f;
      for (int e2 = 0; e2 < 16; ++e2)
        if (!((used >> e2) & 1) && biased[e2] > bv) { bv = biased[e2]; bi = e2; }
      used |= 1u << bi;
      sel[j] = bi; wv[j] = sig[bi]; wsum += sig[bi];
    }
    for (int j = 0; j < 4; ++j) {
      int e2 = sel[j];
      int pos = atomicAdd(&cnt[e2], 1);
      list[e2*T_ + pos] = t;
      wl[e2*T_ + pos] = wv[j] / wsum;
    }
  }
}

__global__ void scan_k(const int* __restrict__ cnt, int* __restrict__ base) {
  if (threadIdx.x == 0 && blockIdx.x == 0) {
    int s = 0;
    for (int e2 = 0; e2 < 16; ++e2) { base[e2] = s; s += cnt[e2]; }
  }
}

// ---------------- GEMM args ----------------
struct GArgs {
  const _Float16* Ah; const _Float16* Al;
  const _Float16* Bh; const _Float16* Bl;
  int M, N, K;
  const int* rowlist; const float* wlist; const int* cnt; const int* base;
  float* C; const float* res; _Float16* act; float* outAt; int ldc;
};

// ---------------- 128x128 GEMM: 512 threads (8 waves, 2x4), counted-vmcnt pipeline ----------------
template<int MODE, bool SPLIT, int DEPTH>
__global__ __launch_bounds__(512, 4) void gemm_k(GArgs p) {
  constexpr int LPS = SPLIT ? 4 : 2;   // loads per stage per thread (1 per tensor)
  const int e = blockIdx.z;
  const int M = p.cnt ? p.cnt[e] : p.M;
  const int m0 = blockIdx.y * 128;
  if (m0 >= M) return;
  const int n0 = blockIdx.x * 128;
  const int tid = threadIdx.x;
  const int wid = tid >> 6, lane = tid & 63;

  __shared__ _Float16 sA[DEPTH][4096];
  __shared__ _Float16 sB[DEPTH][4096];
  __shared__ _Float16 sAl[SPLIT ? DEPTH : 1][SPLIT ? 4096 : 8];
  __shared__ _Float16 sBl[SPLIT ? DEPTH : 1][SPLIT ? 4096 : 8];

  const int srow = tid >> 2;
  const int slot = ((tid & 3) ^ (srow & 3)) * 16;
  const int ldsOff = wid * 1024;
  size_t aIdx;
  if constexpr (MODE == 2) {
    if (p.rowlist) {
      int tok = p.rowlist[(size_t)e * T_ + m0 + srow];
      tok = tok < 0 ? 0 : (tok > T_ - 1 ? T_ - 1 : tok);
      aIdx = (size_t)tok;
    } else aIdx = (size_t)(m0 + srow);
  } else if constexpr (MODE == 3) {
    aIdx = (size_t)p.base[e] + m0 + srow;
  } else {
    aIdx = (size_t)(m0 + srow);
  }
  const char* aPtr  = (const char*)(p.Ah + aIdx * (size_t)p.K) + slot;
  const char* alPtr = SPLIT ? (const char*)(p.Al + aIdx * (size_t)p.K) + slot : aPtr;
  const size_t bIdx = (size_t)e * p.N + n0 + srow;
  const char* bPtr  = (const char*)(p.Bh + bIdx * (size_t)p.K) + slot;
  const char* blPtr = SPLIT ? (const char*)(p.Bl + bIdx * (size_t)p.K) + slot : bPtr;

  auto stage = [&](int buf, int kb) {
    GL16(aPtr + kb, (char*)&sA[buf][0] + ldsOff);
    GL16(bPtr + kb, (char*)&sB[buf][0] + ldsOff);
    if constexpr (SPLIT) {
      GL16(alPtr + kb, (char*)&sAl[buf][0] + ldsOff);
      GL16(blPtr + kb, (char*)&sBl[buf][0] + ldsOff);
    }
  };

  const int wr = (wid >> 2) * 64, wc = (wid & 3) * 32;
  const int fr = lane & 15, fs = lane >> 4;

  f32x4 acc[4][2] = {};
  f32x4 acc2[4][2] = {};

  const int nt = p.K >> 5;
  stage(0, 0);
  if constexpr (DEPTH == 3) { if (nt > 1) stage(1, 64); }

  for (int t = 0; t < nt; ++t) {
    if constexpr (DEPTH == 3) {
      if (t + 2 < nt) stage((t + 2) % 3, (t + 2) * 64);
      __builtin_amdgcn_sched_barrier(0);
      if (t + 2 < nt)      asm volatile("s_waitcnt vmcnt(%0)" :: "i"(2*LPS) : "memory");
      else if (t + 1 < nt) asm volatile("s_waitcnt vmcnt(%0)" :: "i"(LPS)   : "memory");
      else                 asm volatile("s_waitcnt vmcnt(0)" ::: "memory");
    } else {
      if (t + 1 < nt) {
        stage((t + 1) & 1, (t + 1) * 64);
        __builtin_amdgcn_sched_barrier(0);
        asm volatile("s_waitcnt vmcnt(%0)" :: "i"(LPS) : "memory");
      } else {
        __builtin_amdgcn_sched_barrier(0);
        asm volatile("s_waitcnt vmcnt(0)" ::: "memory");
      }
    }
    __builtin_amdgcn_s_barrier();
    __builtin_amdgcn_sched_barrier(0);

    const int cb = (DEPTH == 3) ? (t % 3) : (t & 1);
    half8 ah[4], bh[2], al[4], bl[2];
    #pragma unroll
    for (int i = 0; i < 4; ++i) {
      const int pa = (fs ^ ((wr + i*16 + fr) & 3)) * 8;
      ah[i] = *(const half8*)&sA[cb][(wr + i*16 + fr)*32 + pa];
      if constexpr (SPLIT) al[i] = *(const half8*)&sAl[cb][(wr + i*16 + fr)*32 + pa];
    }
    #pragma unroll
    for (int i = 0; i < 2; ++i) {
      const int pb = (fs ^ ((wc + i*16 + fr) & 3)) * 8;
      bh[i] = *(const half8*)&sB[cb][(wc + i*16 + fr)*32 + pb];
      if constexpr (SPLIT) bl[i] = *(const half8*)&sBl[cb][(wc + i*16 + fr)*32 + pb];
    }
    __builtin_amdgcn_s_setprio(1);
    #pragma unroll
    for (int mi = 0; mi < 4; ++mi) {
      #pragma unroll
      for (int ni = 0; ni < 2; ++ni) {
        acc[mi][ni] = MFMA32(ah[mi], bh[ni], acc[mi][ni]);
        if constexpr (SPLIT) {
          acc2[mi][ni] = MFMA32(ah[mi], bl[ni], acc2[mi][ni]);
          acc2[mi][ni] = MFMA32(al[mi], bh[ni], acc2[mi][ni]);
        }
      }
    }
    __builtin_amdgcn_s_setprio(0);
    __builtin_amdgcn_sched_barrier(0);
    __builtin_amdgcn_s_barrier();
    __builtin_amdgcn_sched_barrier(0);
  }

  const int actld = p.N >> 1;
  #pragma unroll
  for (int mi = 0; mi < 4; ++mi) {
    #pragma unroll
    for (int ni = 0; ni < 2; ++ni) {
      f32x4 v4 = acc[mi][ni];
      if constexpr (SPLIT) v4 = v4 + acc2[mi][ni] * LO_I;
      const int colb = n0 + wc + ni*16 + fr;
      #pragma unroll
      for (int r = 0; r < 4; ++r) {
        const int row = m0 + wr + mi*16 + fs*4 + r;
        float val = v4[r];
        if constexpr (MODE == 0) {
          if (row < M) p.C[(size_t)row * p.ldc + colb] = val;
        } else if constexpr (MODE == 1) {
          if (row < M) p.C[(size_t)row * p.ldc + colb] = p.res[(size_t)row * p.ldc + colb] + val;
        } else if constexpr (MODE == 2) {
          float other = __shfl_xor(val, 1);
          float g = (fr & 1) ? other : val;
          float u = (fr & 1) ? val : other;
          float a = g / (1.0f + expf(-g)) * u;
          if (!(fr & 1) && row < M) {
            size_t ar = (size_t)(p.base ? p.base[e] : 0) + row;
            p.act[ar * (size_t)actld + (colb >> 1)] = (_Float16)a;
          }
        } else {
          if (row < M) {
            int tok = p.rowlist[(size_t)e * T_ + row];
            float w = p.wlist[(size_t)e * T_ + row];
            atomicAdd(&p.outAt[(size_t)tok * p.ldc + colb], val * w);
          }
        }
      }
    }
  }
}

// ---------------- launcher ----------------
extern "C" void kernel_launch(void* const* d_in, const int* in_sizes, int n_in,
                              void* d_out, int out_size, void* d_ws, size_t ws_size,
                              hipStream_t stream) {
  (void)in_sizes; (void)n_in; (void)out_size; (void)ws_size;
  const int*   positions = (const int*)  d_in[0];
  const float* hidden    = (const float*)d_in[1];
  const float* qkv_w     = (const float*)d_in[2];
  const float* o_w       = (const float*)d_in[3];
  const float* q_norm_w  = (const float*)d_in[4];
  const float* k_norm_w  = (const float*)d_in[5];
  const float* ln1_w     = (const float*)d_in[6];
  const float* ln2_w     = (const float*)d_in[7];
  const float* gate_w    = (const float*)d_in[8];
  const float* ebias     = (const float*)d_in[9];
  const float* sgu_w     = (const float*)d_in[10];
  const float* sdown_w   = (const float*)d_in[11];
  const float* egu_w     = (const float*)d_in[12];
  const float* edown_w   = (const float*)d_in[13];
  float* out = (float*)d_out;

  char* wsp = (char*)d_ws;
  size_t off = 0;
  auto alloc = [&](size_t bytes) -> void* {
    void* p = wsp + off;
    off = (off + bytes + 255) & ~(size_t)255;
    return p;
  };
  float*    cosT   = (float*)   alloc((size_t)T_*64*4);
  float*    sinT   = (float*)   alloc((size_t)T_*64*4);
  _Float16* x_h    = (_Float16*)alloc((size_t)T_*H_*2);
  _Float16* x_l    = (_Float16*)alloc((size_t)T_*H_*2);
  float*    qkvb   = (float*)   alloc((size_t)T_*4096*4);
  _Float16* q_h    = (_Float16*)alloc((size_t)NH_*T_*D_*2);
  _Float16* q_l    = (_Float16*)alloc((size_t)NH_*T_*D_*2);
  _Float16* k_h    = (_Float16*)alloc((size_t)NKV_*T_*D_*2);
  _Float16* k_l    = (_Float16*)alloc((size_t)NKV_*T_*D_*2);
  _Float16* vt_h   = (_Float16*)alloc((size_t)NKV_*T_*D_*2);
  _Float16* vt_l   = (_Float16*)alloc((size_t)NKV_*T_*D_*2);
  _Float16* ao_h   = (_Float16*)alloc((size_t)T_*NH_*D_*2);
  _Float16* ao_l   = (_Float16*)alloc((size_t)T_*NH_*D_*2);
  float*    hbuf   = (float*)   alloc((size_t)T_*H_*4);
  _Float16* x2_h   = (_Float16*)alloc((size_t)T_*H_*2);
  _Float16* x2_l   = (_Float16*)alloc((size_t)T_*H_*2);
  _Float16* qkvwT_h= (_Float16*)alloc((size_t)4096*H_*2);
  _Float16* qkvwT_l= (_Float16*)alloc((size_t)4096*H_*2);
  _Float16* owT_h  = (_Float16*)alloc((size_t)H_*H_*2);
  _Float16* owT_l  = (_Float16*)alloc((size_t)H_*H_*2);
  _Float16* sguT   = (_Float16*)alloc((size_t)2*SI_*H_*2);
  _Float16* sdownT = (_Float16*)alloc((size_t)H_*SI_*2);
  _Float16* eguT   = (_Float16*)alloc((size_t)E_*2*I_*H_*2);
  _Float16* edownT = (_Float16*)alloc((size_t)E_*H_*I_*2);
  _Float16* act_s  = (_Float16*)alloc((size_t)T_*SI_*2);
  _Float16* act_e  = (_Float16*)alloc((size_t)(T_*4 + 512)*I_*2);
  int*   cnt   = (int*)  alloc(E_*4);
  int*   ebase = (int*)  alloc(E_*4);
  int*   list  = (int*)  alloc((size_t)E_*T_*4);
  float* wlst  = (float*)alloc((size_t)E_*T_*4);

  hipMemsetAsync(cnt, 0, E_*4, stream);
  tables_k<<<T_, 64, 0, stream>>>(positions, cosT, sinT);

  transpose_k<true ><<<dim3(4096/32, H_/32, 1), 256, 0, stream>>>(qkv_w, qkvwT_h, qkvwT_l, H_, 4096);
  transpose_k<true ><<<dim3(H_/32,  H_/32, 1), 256, 0, stream>>>(o_w, owT_h, owT_l, H_, H_);
  transpose_gu_k    <<<dim3(SI_/16, H_/32, 1), 256, 0, stream>>>(sgu_w, sguT, H_, SI_);
  transpose_k<false><<<dim3(H_/32, SI_/32, 1), 256, 0, stream>>>(sdown_w, sdownT, nullptr, SI_, H_);
  transpose_gu_k    <<<dim3(I_/16,  H_/32, E_), 256, 0, stream>>>(egu_w, eguT, H_, I_);
  transpose_k<false><<<dim3(H_/32,  I_/32, E_), 256, 0, stream>>>(edown_w, edownT, nullptr, I_, H_);

  rmsnorm_k<<<T_, 256, 0, stream>>>(hidden, ln1_w, x_h, x_l);

  { GArgs g{}; g.Ah=x_h; g.Al=x_l; g.Bh=qkvwT_h; g.Bl=qkvwT_l; g.M=T_; g.N=4096; g.K=H_;
    g.C=qkvb; g.ldc=4096;
    gemm_k<0,true,2><<<dim3(4096/128, T_/128, 1), 512, 0, stream>>>(g); }

  qkvpost_k<<<dim3(T_, 32, 1), 128, 0, stream>>>(qkvb, q_norm_w, k_norm_w, cosT, sinT,
                                                 q_h, q_l, k_h, k_l, vt_h, vt_l);

  attn_k<<<dim3(NH_, 32), 256, 0, stream>>>(q_h, q_l, k_h, k_l, vt_h, vt_l, ao_h, ao_l);

  { GArgs g{}; g.Ah=ao_h; g.Al=ao_l; g.Bh=owT_h; g.Bl=owT_l; g.M=T_; g.N=H_; g.K=H_;
    g.C=hbuf; g.res=hidden; g.ldc=H_;
    gemm_k<1,true,2><<<dim3(H_/128, T_/128, 1), 512, 0, stream>>>(g); }

  rmsnorm_k<<<T_, 256, 0, stream>>>(hbuf, ln2_w, x2_h, x2_l);

  router_k<<<T_/4, 256, 0, stream>>>(x2_h, x2_l, gate_w, ebias, cnt, list, wlst);
  scan_k<<<1, 64, 0, stream>>>(cnt, ebase);

  { GArgs g{}; g.Ah=x2_h; g.Bh=sguT; g.M=T_; g.N=2*SI_; g.K=H_; g.act=act_s;
    gemm_k<2,false,3><<<dim3(2*SI_/128, T_/128, 1), 512, 0, stream>>>(g); }

  { GArgs g{}; g.Ah=act_s; g.Bh=sdownT; g.M=T_; g.N=H_; g.K=SI_;
    g.C=out; g.res=hbuf; g.ldc=H_;
    gemm_k<1,false,3><<<dim3(H_/128, T_/128, 1), 512, 0, stream>>>(g); }

  { GArgs g{}; g.Ah=x2_h; g.Bh=eguT; g.M=T_; g.N=2*I_; g.K=H_;
    g.rowlist=list; g.cnt=cnt; g.base=ebase; g.act=act_e;
    gemm_k<2,false,3><<<dim3(2*I_/128, T_/128, E_), 512, 0, stream>>>(g); }

  { GArgs g{}; g.Ah=act_e; g.Bh=edownT; g.M=T_; g.N=H_; g.K=I_;
    g.rowlist=list; g.wlist=wlst; g.cnt=cnt; g.base=ebase;
    g.outAt=out; g.ldc=H_;
    gemm_k<3,false,3><<<dim3(H_/128, T_/128, E_), 512, 0, stream>>>(g); }
}

// Round 11
// 1020.470 us; speedup vs baseline: 1.0101x; 1.0101x over previous
//
#include <hip/hip_runtime.h>
#include <math.h>

#define T_ 2048
#define H_ 2048
#define NH_ 16
#define NKV_ 8
#define D_ 128
#define E_ 16
#define I_ 1024
#define SI_ 1024

typedef _Float16 half8 __attribute__((ext_vector_type(8)));
typedef _Float16 half4_t __attribute__((ext_vector_type(4)));
typedef float f32x4 __attribute__((ext_vector_type(4)));

#define MFMA32(a,b,c) __builtin_amdgcn_mfma_f32_16x16x32_f16((a),(b),(c),0,0,0)

__device__ __constant__ float LO_S = 2048.0f;
__device__ __constant__ float LO_I = 1.0f/2048.0f;
#define EPS_ 1e-5f

#define GL16(gp, lp) __builtin_amdgcn_global_load_lds( \
    (const __attribute__((address_space(1))) unsigned int*)(const void*)(gp), \
    (__attribute__((address_space(3))) unsigned int*)(void*)(lp), 16, 0, 0)

// ---------------- RoPE tables (fp64 for bit-faithful inv_freq) ----------------
__global__ void tables_k(const int* __restrict__ pos, float* __restrict__ cosT, float* __restrict__ sinT) {
  int t = blockIdx.x;
  int j = threadIdx.x; // 0..63
  float pf = (float)pow(10000.0, (double)j / 64.0);
  float invf = 1.0f / pf;
  float ang = (float)pos[t] * invf;
  cosT[t*64 + j] = (float)cos((double)ang);
  sinT[t*64 + j] = (float)sin((double)ang);
}

// ---------------- RMSNorm -> fp16 hi/lo pair ----------------
__global__ __launch_bounds__(256) void rmsnorm_k(const float* __restrict__ x, const float* __restrict__ w,
                                                 _Float16* __restrict__ oh, _Float16* __restrict__ ol) {
  int row = blockIdx.x;
  const float* xr = x + (size_t)row * H_;
  int tid = threadIdx.x;
  float4 a = *(const float4*)(xr + tid*8);
  float4 b = *(const float4*)(xr + tid*8 + 4);
  float ss = a.x*a.x + a.y*a.y + a.z*a.z + a.w*a.w + b.x*b.x + b.y*b.y + b.z*b.z + b.w*b.w;
  #pragma unroll
  for (int m = 1; m < 64; m <<= 1) ss += __shfl_xor(ss, m);
  __shared__ float wsum[4];
  int wid = tid >> 6, lane = tid & 63;
  if (lane == 0) wsum[wid] = ss;
  __syncthreads();
  float tot = wsum[0] + wsum[1] + wsum[2] + wsum[3];
  float rinv = 1.0f / sqrtf(tot / (float)H_ + EPS_);
  const float* av = (const float*)&a;
  const float* bv = (const float*)&b;
  #pragma unroll
  for (int j = 0; j < 8; ++j) {
    float xv = (j < 4) ? av[j] : bv[j-4];
    float val = xv * rinv * w[tid*8 + j];
    _Float16 h = (_Float16)val;
    size_t o = (size_t)row*H_ + tid*8 + j;
    oh[o] = h;
    ol[o] = (_Float16)((val - (float)h) * LO_S);
  }
}

// ---------------- QKV postprocess: q/k rmsnorm + rope, v transpose; split fp16 ----------------
__global__ __launch_bounds__(128) void qkvpost_k(
    const float* __restrict__ qkv, const float* __restrict__ qnw, const float* __restrict__ knw,
    const float* __restrict__ cosT, const float* __restrict__ sinT,
    _Float16* __restrict__ qh, _Float16* __restrict__ ql,
    _Float16* __restrict__ kh, _Float16* __restrict__ kl,
    _Float16* __restrict__ vth, _Float16* __restrict__ vtl) {
  int t = blockIdx.x, u = blockIdx.y, d = threadIdx.x;
  float val = qkv[(size_t)t*4096 + u*128 + d];
  __shared__ float sv[128];
  __shared__ float ssum[2];
  if (u < 24) {
    float ss = val * val;
    #pragma unroll
    for (int m = 1; m < 64; m <<= 1) ss += __shfl_xor(ss, m);
    if ((d & 63) == 0) ssum[d >> 6] = ss;
    __syncthreads();
    float rinv = 1.0f / sqrtf((ssum[0] + ssum[1]) / 128.0f + EPS_);
    const float* nw = (u < 16) ? qnw : knw;
    float nv = val * rinv * nw[d];
    sv[d] = nv;
    __syncthreads();
    int j = d & 63;
    float c = cosT[t*64 + j], s = sinT[t*64 + j];
    float x1 = sv[j], x2 = sv[j + 64];
    float o = (d < 64) ? (x1*c - x2*s) : (x2*c + x1*s);
    _Float16 hv = (_Float16)o;
    _Float16 lv = (_Float16)((o - (float)hv) * LO_S);
    if (u < 16) { size_t off = ((size_t)u*T_ + t)*D_ + d; qh[off] = hv; ql[off] = lv; }
    else { size_t off = ((size_t)(u-16)*T_ + t)*D_ + d; kh[off] = hv; kl[off] = lv; }
  } else {
    int kv = u - 24;
    _Float16 hv = (_Float16)val;
    _Float16 lv = (_Float16)((val - (float)hv) * LO_S);
    size_t off = ((size_t)kv*D_ + d)*T_ + t;
    vth[off] = hv; vtl[off] = lv;
  }
}

// ---------------- weight transpose + fp16 convert (optional split) ----------------
template<bool SPL>
__global__ __launch_bounds__(256) void transpose_k(const float* __restrict__ in, _Float16* __restrict__ oh,
                                                   _Float16* __restrict__ ol, int R, int C) {
  size_t zo = (size_t)blockIdx.z * R * C;
  in += zo; oh += zo; if (SPL) ol += zo;
  __shared__ float tile[32][33];
  int c0 = blockIdx.x*32, r0 = blockIdx.y*32;
  int tid = threadIdx.x;
  int lr = tid >> 3;
  int lc = (tid & 7) * 4;
  float4 v = *(const float4*)(in + (size_t)(r0+lr)*C + c0 + lc);
  tile[lr][lc+0]=v.x; tile[lr][lc+1]=v.y; tile[lr][lc+2]=v.z; tile[lr][lc+3]=v.w;
  __syncthreads();
  half4_t hv, lv;
  #pragma unroll
  for (int j = 0; j < 4; ++j) {
    float f = tile[lc+j][lr];
    _Float16 h = (_Float16)f;
    hv[j] = h;
    if (SPL) lv[j] = (_Float16)((f - (float)h) * LO_S);
  }
  size_t ob = (size_t)(c0+lr)*R + r0 + lc;
  *(half4_t*)(oh + ob) = hv;
  if (SPL) *(half4_t*)(ol + ob) = lv;
}

// gate/up interleaving transpose: out[2j+p][h] = in[h][j + p*Ih]
__global__ __launch_bounds__(256) void transpose_gu_k(const float* __restrict__ in, _Float16* __restrict__ out,
                                                      int R, int Ih) {
  size_t zi = (size_t)blockIdx.z * R * 2 * Ih;
  in += zi; out += zi;
  __shared__ float tg[32][17], tu[32][17];
  int j0 = blockIdx.x*16, h0 = blockIdx.y*32;
  int tid = threadIdx.x;
  int lh = tid >> 3;
  int lj = (tid & 7) * 2;
  int C = 2*Ih;
  float2 g = *(const float2*)(in + (size_t)(h0+lh)*C + j0 + lj);
  float2 u = *(const float2*)(in + (size_t)(h0+lh)*C + Ih + j0 + lj);
  tg[lh][lj]=g.x; tg[lh][lj+1]=g.y; tu[lh][lj]=u.x; tu[lh][lj+1]=u.y;
  __syncthreads();
  int orow = tid >> 3;
  int oj = orow >> 1, op = orow & 1;
  int oc = (tid & 7) * 4;
  float (*sel)[17] = op ? tu : tg;
  half4_t pack;
  #pragma unroll
  for (int q = 0; q < 4; ++q) pack[q] = (_Float16)sel[oc+q][oj];
  *(half4_t*)(out + (size_t)(2*(j0+oj)+op)*R + h0 + oc) = pack;
}

// ---------------- flash attention: balanced unpaired tiles, dbuf LDS, defer-max ----------------
__global__ __launch_bounds__(256) void attn_k(
    const _Float16* __restrict__ qh_, const _Float16* __restrict__ ql_,
    const _Float16* __restrict__ kh_, const _Float16* __restrict__ kl_,
    const _Float16* __restrict__ vh_, const _Float16* __restrict__ vl_,
    _Float16* __restrict__ aoh, _Float16* __restrict__ aol) {
  __shared__ _Float16 sK [2][4096];
  __shared__ _Float16 sKl[2][4096];
  __shared__ _Float16 sV [2][4096];
  __shared__ _Float16 sVl[2][4096];
  const int head = blockIdx.x;
  // balanced remap: blocks b and b+256 (same CU slot under round-robin) get tiles
  // summing to 31 -> every CU sees 66 chunks total (was 36..96).
  const int y = blockIdx.y;
  const int tile = (y < 16) ? (31 - 2*y) : (2*(y-16));
  const int kvh = head >> 1;
  const int wid = threadIdx.x >> 6, lane = threadIdx.x & 63;
  const int fr = lane & 15, fs = lane >> 4;
  const float scale = 0.08838834764831845f;

  const char* kbC  = (const char*)(kh_ + (size_t)kvh*T_*D_);
  const char* kbCl = (const char*)(kl_ + (size_t)kvh*T_*D_);
  const char* vbC  = (const char*)(vh_ + (size_t)kvh*D_*T_);
  const char* vbCl = (const char*)(vl_ + (size_t)kvh*D_*T_);

  // K: row r (256B), 16B-unit u, source unit u^(r&7).
  // V^T: row d (64B), unit uv, source unit uv^((d>>2)&3)  [bits b2,b3 of d -> 2-way only]
  auto stage = [&](int buf, int kvt) {
    #pragma unroll
    for (int i = 0; i < 2; ++i) {
      const int off  = wid*2048 + i*1024;
      const int loff = off + lane*16;
      const int r  = loff >> 8;
      const int u  = (loff >> 4) & 15;
      const int us = u ^ (r & 7);
      const size_t gb = ((size_t)(kvt + r) << 8) + ((size_t)us << 4);
      GL16(kbC  + gb, (char*)&sK [buf][0] + off);
      GL16(kbCl + gb, (char*)&sKl[buf][0] + off);
      const int d   = loff >> 6;
      const int uv  = (loff >> 4) & 3;
      const int uvs = uv ^ ((d >> 2) & 3);
      const size_t gvb = (size_t)d*(T_*2) + (size_t)kvt*2 + ((size_t)uvs << 4);
      GL16(vbC  + gvb, (char*)&sV [buf][0] + off);
      GL16(vbCl + gvb, (char*)&sVl[buf][0] + off);
    }
  };

  const int q0 = tile*64 + wid*16;
  const int qrow = q0 + fr;
  const _Float16* qb_  = qh_ + ((size_t)head*T_ + qrow)*D_;
  const _Float16* qlb_ = ql_ + ((size_t)head*T_ + qrow)*D_;
  half8 qf[4], qfl[4];
  #pragma unroll
  for (int s = 0; s < 4; ++s) {
    qf[s]  = *(const half8*)(qb_  + s*32 + fs*8);
    qfl[s] = *(const half8*)(qlb_ + s*32 + fs*8);
  }
  float m = -1e30f, lsum = 0.f;
  f32x4 oacc[8] = {};
  f32x4 oacc2[8] = {};
  const int nc = 2*tile + 2;

  stage(0, 0);
  #pragma unroll 1
  for (int c = 0; c < nc; ++c) {
    const int kvt = c*32;
    const int buf = c & 1;
    __syncthreads();
    if (c + 1 < nc) stage(buf ^ 1, kvt + 32);

    f32x4 sa = {0,0,0,0}, sa2 = {0,0,0,0}, sb = {0,0,0,0}, sb2 = {0,0,0,0};
    __builtin_amdgcn_s_setprio(1);
    #pragma unroll
    for (int s = 0; s < 4; ++s) {
      const int rA = fr, rB = fr + 16;
      const int eA = (((4*s + fs) ^ (rA & 7)) << 3);
      const int eB = (((4*s + fs) ^ (rB & 7)) << 3);
      half8 kfA  = *(const half8*)&sK [buf][rA*128 + eA];
      half8 kflA = *(const half8*)&sKl[buf][rA*128 + eA];
      half8 kfB  = *(const half8*)&sK [buf][rB*128 + eB];
      half8 kflB = *(const half8*)&sKl[buf][rB*128 + eB];
      sa  = MFMA32(kfA, qf[s], sa);
      sa2 = MFMA32(kfA, qfl[s], sa2);
      sa2 = MFMA32(kflA, qf[s], sa2);
      sb  = MFMA32(kfB, qf[s], sb);
      sb2 = MFMA32(kfB, qfl[s], sb2);
      sb2 = MFMA32(kflB, qf[s], sb2);
    }
    __builtin_amdgcn_s_setprio(0);

    float sv[8];
    #pragma unroll
    for (int r = 0; r < 4; ++r) {
      float xA = (sa[r] + sa2[r]*LO_I) * scale;
      sv[r] = (kvt + fs*4 + r > qrow) ? -INFINITY : xA;
      float xB = (sb[r] + sb2[r]*LO_I) * scale;
      sv[4+r] = (kvt + 16 + fs*4 + r > qrow) ? -INFINITY : xB;
    }
    float tm = -INFINITY;
    #pragma unroll
    for (int j = 0; j < 8; ++j) tm = fmaxf(tm, sv[j]);
    tm = fmaxf(tm, __shfl_xor(tm, 16));
    tm = fmaxf(tm, __shfl_xor(tm, 32));
    // defer-max (T13): rescale only when the max grew by >8; P bounded by e^8
    // (fits fp16 hi/lo; exact online-softmax reformulation).
    if (tm > m + 8.f) {
      float f = __expf(m - tm);
      lsum *= f;
      #pragma unroll
      for (int db = 0; db < 8; ++db) { oacc[db] *= f; oacc2[db] *= f; }
      m = tm;
    }
    float p[8]; float ps = 0.f;
    #pragma unroll
    for (int j = 0; j < 8; ++j) { p[j] = __expf(sv[j] - m); ps += p[j]; }
    ps += __shfl_xor(ps, 16);
    ps += __shfl_xor(ps, 32);
    lsum += ps;
    half8 ph, pl;
    #pragma unroll
    for (int j = 0; j < 8; ++j) {
      _Float16 hp = (_Float16)p[j];
      ph[j] = hp;
      pl[j] = (_Float16)((p[j] - (float)hp) * LO_S);
    }

    __builtin_amdgcn_s_setprio(1);
    #pragma unroll
    for (int db = 0; db < 8; ++db) {
      const int d0 = db*16 + fr;
      const int base = d0*32;
      const int sw = (d0 >> 2) & 3;
      const int e1 = ((((fs>>1)    ) ^ sw) << 3) + (fs & 1)*4;
      const int e2 = (((2 + (fs>>1)) ^ sw) << 3) + (fs & 1)*4;
      half4_t v0  = *(const half4_t*)&sV [buf][base + e1];
      half4_t v1  = *(const half4_t*)&sV [buf][base + e2];
      half4_t v0l = *(const half4_t*)&sVl[buf][base + e1];
      half4_t v1l = *(const half4_t*)&sVl[buf][base + e2];
      half8 vf, vfl;
      #pragma unroll
      for (int j = 0; j < 4; ++j) { vf[j] = v0[j]; vf[4+j] = v1[j]; vfl[j] = v0l[j]; vfl[4+j] = v1l[j]; }
      oacc[db]  = MFMA32(vf, ph, oacc[db]);
      oacc2[db] = MFMA32(vf, pl, oacc2[db]);
      oacc2[db] = MFMA32(vfl, ph, oacc2[db]);
    }
    __builtin_amdgcn_s_setprio(0);
  }

  float inv = 1.0f / lsum;
  #pragma unroll
  for (int db = 0; db < 8; ++db) {
    #pragma unroll
    for (int r = 0; r < 4; ++r) {
      float val = (oacc[db][r] + oacc2[db][r]*LO_I) * inv;
      int dd = db*16 + fs*4 + r;
      size_t off = (size_t)qrow*(NH_*D_) + head*D_ + dd;
      _Float16 hv = (_Float16)val;
      aoh[off] = hv;
      aol[off] = (_Float16)((val - (float)hv) * LO_S);
    }
  }
}

// ---------------- router: fp32 logits, sigmoid, top-4, dispatch lists ----------------
__global__ __launch_bounds__(256) void router_k(const _Float16* __restrict__ x2h, const _Float16* __restrict__ x2l,
    const float* __restrict__ gw, const float* __restrict__ eb,
    int* __restrict__ cnt, int* __restrict__ list, float* __restrict__ wl) {
  int t = blockIdx.x*4 + (threadIdx.x >> 6);
  int lane = threadIdx.x & 63;
  const _Float16* xh = x2h + (size_t)t*H_;
  const _Float16* xl = x2l + (size_t)t*H_;
  f32x4 a0 = {0,0,0,0}, a1 = {0,0,0,0}, a2 = {0,0,0,0}, a3 = {0,0,0,0};
  for (int h = lane; h < H_; h += 64) {
    float xv = (float)xh[h] + (float)xl[h] * LO_I;
    const float* g = gw + (size_t)h*16;
    a0 += xv * (*(const f32x4*)(g));
    a1 += xv * (*(const f32x4*)(g+4));
    a2 += xv * (*(const f32x4*)(g+8));
    a3 += xv * (*(const f32x4*)(g+12));
  }
  float acc[16];
  #pragma unroll
  for (int j = 0; j < 4; ++j) { acc[j]=a0[j]; acc[4+j]=a1[j]; acc[8+j]=a2[j]; acc[12+j]=a3[j]; }
  #pragma unroll
  for (int mm = 1; mm < 64; mm <<= 1) {
    #pragma unroll
    for (int e2 = 0; e2 < 16; ++e2) acc[e2] += __shfl_xor(acc[e2], mm);
  }
  if (lane == 0) {
    float sig[16], biased[16];
    #pragma unroll
    for (int e2 = 0; e2 < 16; ++e2) {
      float s = 1.0f / (1.0f + expf(-acc[e2]));
      sig[e2] = s; biased[e2] = s + eb[e2];
    }
    int sel[4]; float wv[4]; float wsum = 0.f;
    unsigned used = 0;
    for (int j = 0; j < 4; ++j) {
      int bi = -1; float bv = -1e30f;
      for (int e2 = 0; e2 < 16; ++e2)
        if (!((used >> e2) & 1) && biased[e2] > bv) { bv = biased[e2]; bi = e2; }
      used |= 1u << bi;
      sel[j] = bi; wv[j] = sig[bi]; wsum += sig[bi];
    }
    for (int j = 0; j < 4; ++j) {
      int e2 = sel[j];
      int pos = atomicAdd(&cnt[e2], 1);
      list[e2*T_ + pos] = t;
      wl[e2*T_ + pos] = wv[j] / wsum;
    }
  }
}

__global__ void scan_k(const int* __restrict__ cnt, int* __restrict__ base) {
  if (threadIdx.x == 0 && blockIdx.x == 0) {
    int s = 0;
    for (int e2 = 0; e2 < 16; ++e2) { base[e2] = s; s += cnt[e2]; }
  }
}

// ---------------- GEMM args ----------------
struct GArgs {
  const _Float16* Ah; const _Float16* Al;
  const _Float16* Bh; const _Float16* Bl;
  int M, N, K;
  const int* rowlist; const float* wlist; const int* cnt; const int* base;
  float* C; const float* res; _Float16* act; float* outAt; int ldc;
};

// ---------------- 128x128 GEMM: 512 threads (8 waves, 2x4), counted-vmcnt pipeline ----------------
template<int MODE, bool SPLIT, int DEPTH>
__global__ __launch_bounds__(512, 4) void gemm_k(GArgs p) {
  constexpr int LPS = SPLIT ? 4 : 2;   // loads per stage per thread (1 per tensor)
  const int e = blockIdx.z;
  const int M = p.cnt ? p.cnt[e] : p.M;
  const int m0 = blockIdx.y * 128;
  if (m0 >= M) return;
  const int n0 = blockIdx.x * 128;
  const int tid = threadIdx.x;
  const int wid = tid >> 6, lane = tid & 63;

  __shared__ _Float16 sA[DEPTH][4096];
  __shared__ _Float16 sB[DEPTH][4096];
  __shared__ _Float16 sAl[SPLIT ? DEPTH : 1][SPLIT ? 4096 : 8];
  __shared__ _Float16 sBl[SPLIT ? DEPTH : 1][SPLIT ? 4096 : 8];

  const int srow = tid >> 2;
  const int slot = ((tid & 3) ^ (srow & 3)) * 16;
  const int ldsOff = wid * 1024;
  size_t aIdx;
  if constexpr (MODE == 2) {
    if (p.rowlist) {
      int tok = p.rowlist[(size_t)e * T_ + m0 + srow];
      tok = tok < 0 ? 0 : (tok > T_ - 1 ? T_ - 1 : tok);
      aIdx = (size_t)tok;
    } else aIdx = (size_t)(m0 + srow);
  } else if constexpr (MODE == 3) {
    aIdx = (size_t)p.base[e] + m0 + srow;
  } else {
    aIdx = (size_t)(m0 + srow);
  }
  const char* aPtr  = (const char*)(p.Ah + aIdx * (size_t)p.K) + slot;
  const char* alPtr = SPLIT ? (const char*)(p.Al + aIdx * (size_t)p.K) + slot : aPtr;
  const size_t bIdx = (size_t)e * p.N + n0 + srow;
  const char* bPtr  = (const char*)(p.Bh + bIdx * (size_t)p.K) + slot;
  const char* blPtr = SPLIT ? (const char*)(p.Bl + bIdx * (size_t)p.K) + slot : bPtr;

  auto stage = [&](int buf, int kb) {
    GL16(aPtr + kb, (char*)&sA[buf][0] + ldsOff);
    GL16(bPtr + kb, (char*)&sB[buf][0] + ldsOff);
    if constexpr (SPLIT) {
      GL16(alPtr + kb, (char*)&sAl[buf][0] + ldsOff);
      GL16(blPtr + kb, (char*)&sBl[buf][0] + ldsOff);
    }
  };

  const int wr = (wid >> 2) * 64, wc = (wid & 3) * 32;
  const int fr = lane & 15, fs = lane >> 4;

  f32x4 acc[4][2] = {};
  f32x4 acc2[4][2] = {};

  const int nt = p.K >> 5;
  stage(0, 0);
  if constexpr (DEPTH == 3) { if (nt > 1) stage(1, 64); }

  for (int t = 0; t < nt; ++t) {
    if constexpr (DEPTH == 3) {
      if (t + 2 < nt) stage((t + 2) % 3, (t + 2) * 64);
      __builtin_amdgcn_sched_barrier(0);
      if (t + 2 < nt)      asm volatile("s_waitcnt vmcnt(%0)" :: "i"(2*LPS) : "memory");
      else if (t + 1 < nt) asm volatile("s_waitcnt vmcnt(%0)" :: "i"(LPS)   : "memory");
      else                 asm volatile("s_waitcnt vmcnt(0)" ::: "memory");
    } else {
      if (t + 1 < nt) {
        stage((t + 1) & 1, (t + 1) * 64);
        __builtin_amdgcn_sched_barrier(0);
        asm volatile("s_waitcnt vmcnt(%0)" :: "i"(LPS) : "memory");
      } else {
        __builtin_amdgcn_sched_barrier(0);
        asm volatile("s_waitcnt vmcnt(0)" ::: "memory");
      }
    }
    __builtin_amdgcn_s_barrier();
    __builtin_amdgcn_sched_barrier(0);

    const int cb = (DEPTH == 3) ? (t % 3) : (t & 1);
    half8 ah[4], bh[2], al[4], bl[2];
    #pragma unroll
    for (int i = 0; i < 4; ++i) {
      const int pa = (fs ^ ((wr + i*16 + fr) & 3)) * 8;
      ah[i] = *(const half8*)&sA[cb][(wr + i*16 + fr)*32 + pa];
      if constexpr (SPLIT) al[i] = *(const half8*)&sAl[cb][(wr + i*16 + fr)*32 + pa];
    }
    #pragma unroll
    for (int i = 0; i < 2; ++i) {
      const int pb = (fs ^ ((wc + i*16 + fr) & 3)) * 8;
      bh[i] = *(const half8*)&sB[cb][(wc + i*16 + fr)*32 + pb];
      if constexpr (SPLIT) bl[i] = *(const half8*)&sBl[cb][(wc + i*16 + fr)*32 + pb];
    }
    __builtin_amdgcn_s_setprio(1);
    #pragma unroll
    for (int mi = 0; mi < 4; ++mi) {
      #pragma unroll
      for (int ni = 0; ni < 2; ++ni) {
        acc[mi][ni] = MFMA32(ah[mi], bh[ni], acc[mi][ni]);
        if constexpr (SPLIT) {
          acc2[mi][ni] = MFMA32(ah[mi], bl[ni], acc2[mi][ni]);
          acc2[mi][ni] = MFMA32(al[mi], bh[ni], acc2[mi][ni]);
        }
      }
    }
    __builtin_amdgcn_s_setprio(0);
    __builtin_amdgcn_sched_barrier(0);
    __builtin_amdgcn_s_barrier();
    __builtin_amdgcn_sched_barrier(0);
  }

  const int actld = p.N >> 1;
  #pragma unroll
  for (int mi = 0; mi < 4; ++mi) {
    #pragma unroll
    for (int ni = 0; ni < 2; ++ni) {
      f32x4 v4 = acc[mi][ni];
      if constexpr (SPLIT) v4 = v4 + acc2[mi][ni] * LO_I;
      const int colb = n0 + wc + ni*16 + fr;
      #pragma unroll
      for (int r = 0; r < 4; ++r) {
        const int row = m0 + wr + mi*16 + fs*4 + r;
        float val = v4[r];
        if constexpr (MODE == 0) {
          if (row < M) p.C[(size_t)row * p.ldc + colb] = val;
        } else if constexpr (MODE == 1) {
          if (row < M) p.C[(size_t)row * p.ldc + colb] = p.res[(size_t)row * p.ldc + colb] + val;
        } else if constexpr (MODE == 2) {
          float other = __shfl_xor(val, 1);
          float g = (fr & 1) ? other : val;
          float u = (fr & 1) ? val : other;
          float a = g / (1.0f + __expf(-g)) * u;
          if (!(fr & 1) && row < M) {
            size_t ar = (size_t)(p.base ? p.base[e] : 0) + row;
            p.act[ar * (size_t)actld + (colb >> 1)] = (_Float16)a;
          }
        } else {
          if (row < M) {
            int tok = p.rowlist[(size_t)e * T_ + row];
            float w = p.wlist[(size_t)e * T_ + row];
            atomicAdd(&p.outAt[(size_t)tok * p.ldc + colb], val * w);
          }
        }
      }
    }
  }
}

// ---------------- launcher ----------------
extern "C" void kernel_launch(void* const* d_in, const int* in_sizes, int n_in,
                              void* d_out, int out_size, void* d_ws, size_t ws_size,
                              hipStream_t stream) {
  (void)in_sizes; (void)n_in; (void)out_size; (void)ws_size;
  const int*   positions = (const int*)  d_in[0];
  const float* hidden    = (const float*)d_in[1];
  const float* qkv_w     = (const float*)d_in[2];
  const float* o_w       = (const float*)d_in[3];
  const float* q_norm_w  = (const float*)d_in[4];
  const float* k_norm_w  = (const float*)d_in[5];
  const float* ln1_w     = (const float*)d_in[6];
  const float* ln2_w     = (const float*)d_in[7];
  const float* gate_w    = (const float*)d_in[8];
  const float* ebias     = (const float*)d_in[9];
  const float* sgu_w     = (const float*)d_in[10];
  const float* sdown_w   = (const float*)d_in[11];
  const float* egu_w     = (const float*)d_in[12];
  const float* edown_w   = (const float*)d_in[13];
  float* out = (float*)d_out;

  char* wsp = (char*)d_ws;
  size_t off = 0;
  auto alloc = [&](size_t bytes) -> void* {
    void* p = wsp + off;
    off = (off + bytes + 255) & ~(size_t)255;
    return p;
  };
  float*    cosT   = (float*)   alloc((size_t)T_*64*4);
  float*    sinT   = (float*)   alloc((size_t)T_*64*4);
  _Float16* x_h    = (_Float16*)alloc((size_t)T_*H_*2);
  _Float16* x_l    = (_Float16*)alloc((size_t)T_*H_*2);
  float*    qkvb   = (float*)   alloc((size_t)T_*4096*4);
  _Float16* q_h    = (_Float16*)alloc((size_t)NH_*T_*D_*2);
  _Float16* q_l    = (_Float16*)alloc((size_t)NH_*T_*D_*2);
  _Float16* k_h    = (_Float16*)alloc((size_t)NKV_*T_*D_*2);
  _Float16* k_l    = (_Float16*)alloc((size_t)NKV_*T_*D_*2);
  _Float16* vt_h   = (_Float16*)alloc((size_t)NKV_*T_*D_*2);
  _Float16* vt_l   = (_Float16*)alloc((size_t)NKV_*T_*D_*2);
  _Float16* ao_h   = (_Float16*)alloc((size_t)T_*NH_*D_*2);
  _Float16* ao_l   = (_Float16*)alloc((size_t)T_*NH_*D_*2);
  float*    hbuf   = (float*)   alloc((size_t)T_*H_*4);
  _Float16* x2_h   = (_Float16*)alloc((size_t)T_*H_*2);
  _Float16* x2_l   = (_Float16*)alloc((size_t)T_*H_*2);
  _Float16* qkvwT_h= (_Float16*)alloc((size_t)4096*H_*2);
  _Float16* qkvwT_l= (_Float16*)alloc((size_t)4096*H_*2);
  _Float16* owT_h  = (_Float16*)alloc((size_t)H_*H_*2);
  _Float16* owT_l  = (_Float16*)alloc((size_t)H_*H_*2);
  _Float16* sguT   = (_Float16*)alloc((size_t)2*SI_*H_*2);
  _Float16* sdownT = (_Float16*)alloc((size_t)H_*SI_*2);
  _Float16* eguT   = (_Float16*)alloc((size_t)E_*2*I_*H_*2);
  _Float16* edownT = (_Float16*)alloc((size_t)E_*H_*I_*2);
  _Float16* act_s  = (_Float16*)alloc((size_t)T_*SI_*2);
  _Float16* act_e  = (_Float16*)alloc((size_t)(T_*4 + 512)*I_*2);
  int*   cnt   = (int*)  alloc(E_*4);
  int*   ebase = (int*)  alloc(E_*4);
  int*   list  = (int*)  alloc((size_t)E_*T_*4);
  float* wlst  = (float*)alloc((size_t)E_*T_*4);

  hipMemsetAsync(cnt, 0, E_*4, stream);
  tables_k<<<T_, 64, 0, stream>>>(positions, cosT, sinT);

  transpose_k<true ><<<dim3(4096/32, H_/32, 1), 256, 0, stream>>>(qkv_w, qkvwT_h, qkvwT_l, H_, 4096);
  transpose_k<true ><<<dim3(H_/32,  H_/32, 1), 256, 0, stream>>>(o_w, owT_h, owT_l, H_, H_);
  transpose_gu_k    <<<dim3(SI_/16, H_/32, 1), 256, 0, stream>>>(sgu_w, sguT, H_, SI_);
  transpose_k<false><<<dim3(H_/32, SI_/32, 1), 256, 0, stream>>>(sdown_w, sdownT, nullptr, SI_, H_);
  transpose_gu_k    <<<dim3(I_/16,  H_/32, E_), 256, 0, stream>>>(egu_w, eguT, H_, I_);
  transpose_k<false><<<dim3(H_/32,  I_/32, E_), 256, 0, stream>>>(edown_w, edownT, nullptr, I_, H_);

  rmsnorm_k<<<T_, 256, 0, stream>>>(hidden, ln1_w, x_h, x_l);

  { GArgs g{}; g.Ah=x_h; g.Al=x_l; g.Bh=qkvwT_h; g.Bl=qkvwT_l; g.M=T_; g.N=4096; g.K=H_;
    g.C=qkvb; g.ldc=4096;
    gemm_k<0,true,2><<<dim3(4096/128, T_/128, 1), 512, 0, stream>>>(g); }

  qkvpost_k<<<dim3(T_, 32, 1), 128, 0, stream>>>(qkvb, q_norm_w, k_norm_w, cosT, sinT,
                                                 q_h, q_l, k_h, k_l, vt_h, vt_l);

  attn_k<<<dim3(NH_, 32), 256, 0, stream>>>(q_h, q_l, k_h, k_l, vt_h, vt_l, ao_h, ao_l);

  { GArgs g{}; g.Ah=ao_h; g.Al=ao_l; g.Bh=owT_h; g.Bl=owT_l; g.M=T_; g.N=H_; g.K=H_;
    g.C=hbuf; g.res=hidden; g.ldc=H_;
    gemm_k<1,true,2><<<dim3(H_/128, T_/128, 1), 512, 0, stream>>>(g); }

  rmsnorm_k<<<T_, 256, 0, stream>>>(hbuf, ln2_w, x2_h, x2_l);

  router_k<<<T_/4, 256, 0, stream>>>(x2_h, x2_l, gate_w, ebias, cnt, list, wlst);
  scan_k<<<1, 64, 0, stream>>>(cnt, ebase);

  { GArgs g{}; g.Ah=x2_h; g.Bh=sguT; g.M=T_; g.N=2*SI_; g.K=H_; g.act=act_s;
    gemm_k<2,false,3><<<dim3(2*SI_/128, T_/128, 1), 512, 0, stream>>>(g); }

  { GArgs g{}; g.Ah=act_s; g.Bh=sdownT; g.M=T_; g.N=H_; g.K=SI_;
    g.C=out; g.res=hbuf; g.ldc=H_;
    gemm_k<1,false,3><<<dim3(H_/128, T_/128, 1), 512, 0, stream>>>(g); }

  { GArgs g{}; g.Ah=x2_h; g.Bh=eguT; g.M=T_; g.N=2*I_; g.K=H_;
    g.rowlist=list; g.cnt=cnt; g.base=ebase; g.act=act_e;
    gemm_k<2,false,3><<<dim3(2*I_/128, T_/128, E_), 512, 0, stream>>>(g); }

  { GArgs g{}; g.Ah=act_e; g.Bh=edownT; g.M=T_; g.N=H_; g.K=I_;
    g.rowlist=list; g.wlist=wlst; g.cnt=cnt; g.base=ebase;
    g.outAt=out; g.ldc=H_;
    gemm_k<3,false,3><<<dim3(H_/128, T_/128, E_), 512, 0, stream>>>(g); }
}

// Round 12
// 994.859 us; speedup vs baseline: 1.0361x; 1.0257x over previous
//
#include <hip/hip_runtime.h>
#include <math.h>

#define T_ 2048
#define H_ 2048
#define NH_ 16
#define NKV_ 8
#define D_ 128
#define E_ 16
#define I_ 1024
#define SI_ 1024

typedef _Float16 half8 __attribute__((ext_vector_type(8)));
typedef _Float16 half4_t __attribute__((ext_vector_type(4)));
typedef float f32x4 __attribute__((ext_vector_type(4)));

#define MFMA32(a,b,c) __builtin_amdgcn_mfma_f32_16x16x32_f16((a),(b),(c),0,0,0)

__device__ __constant__ float LO_S = 2048.0f;
__device__ __constant__ float LO_I = 1.0f/2048.0f;
#define EPS_ 1e-5f

#define GL16(gp, lp) __builtin_amdgcn_global_load_lds( \
    (const __attribute__((address_space(1))) unsigned int*)(const void*)(gp), \
    (__attribute__((address_space(3))) unsigned int*)(void*)(lp), 16, 0, 0)

// ---------------- RoPE tables (fp64 for bit-faithful inv_freq) ----------------
__global__ void tables_k(const int* __restrict__ pos, float* __restrict__ cosT, float* __restrict__ sinT) {
  int t = blockIdx.x;
  int j = threadIdx.x; // 0..63
  float pf = (float)pow(10000.0, (double)j / 64.0);
  float invf = 1.0f / pf;
  float ang = (float)pos[t] * invf;
  cosT[t*64 + j] = (float)cos((double)ang);
  sinT[t*64 + j] = (float)sin((double)ang);
}

// ---------------- RMSNorm -> fp16 hi/lo pair ----------------
__global__ __launch_bounds__(256) void rmsnorm_k(const float* __restrict__ x, const float* __restrict__ w,
                                                 _Float16* __restrict__ oh, _Float16* __restrict__ ol) {
  int row = blockIdx.x;
  const float* xr = x + (size_t)row * H_;
  int tid = threadIdx.x;
  float4 a = *(const float4*)(xr + tid*8);
  float4 b = *(const float4*)(xr + tid*8 + 4);
  float ss = a.x*a.x + a.y*a.y + a.z*a.z + a.w*a.w + b.x*b.x + b.y*b.y + b.z*b.z + b.w*b.w;
  #pragma unroll
  for (int m = 1; m < 64; m <<= 1) ss += __shfl_xor(ss, m);
  __shared__ float wsum[4];
  int wid = tid >> 6, lane = tid & 63;
  if (lane == 0) wsum[wid] = ss;
  __syncthreads();
  float tot = wsum[0] + wsum[1] + wsum[2] + wsum[3];
  float rinv = 1.0f / sqrtf(tot / (float)H_ + EPS_);
  const float* av = (const float*)&a;
  const float* bv = (const float*)&b;
  #pragma unroll
  for (int j = 0; j < 8; ++j) {
    float xv = (j < 4) ? av[j] : bv[j-4];
    float val = xv * rinv * w[tid*8 + j];
    _Float16 h = (_Float16)val;
    size_t o = (size_t)row*H_ + tid*8 + j;
    oh[o] = h;
    ol[o] = (_Float16)((val - (float)h) * LO_S);
  }
}

// ---------------- QKV postprocess: q/k rmsnorm + rope, v transpose; split fp16 ----------------
__global__ __launch_bounds__(128) void qkvpost_k(
    const float* __restrict__ qkv, const float* __restrict__ qnw, const float* __restrict__ knw,
    const float* __restrict__ cosT, const float* __restrict__ sinT,
    _Float16* __restrict__ qh, _Float16* __restrict__ ql,
    _Float16* __restrict__ kh, _Float16* __restrict__ kl,
    _Float16* __restrict__ vth, _Float16* __restrict__ vtl) {
  int t = blockIdx.x, u = blockIdx.y, d = threadIdx.x;
  float val = qkv[(size_t)t*4096 + u*128 + d];
  __shared__ float sv[128];
  __shared__ float ssum[2];
  if (u < 24) {
    float ss = val * val;
    #pragma unroll
    for (int m = 1; m < 64; m <<= 1) ss += __shfl_xor(ss, m);
    if ((d & 63) == 0) ssum[d >> 6] = ss;
    __syncthreads();
    float rinv = 1.0f / sqrtf((ssum[0] + ssum[1]) / 128.0f + EPS_);
    const float* nw = (u < 16) ? qnw : knw;
    float nv = val * rinv * nw[d];
    sv[d] = nv;
    __syncthreads();
    int j = d & 63;
    float c = cosT[t*64 + j], s = sinT[t*64 + j];
    float x1 = sv[j], x2 = sv[j + 64];
    float o = (d < 64) ? (x1*c - x2*s) : (x2*c + x1*s);
    _Float16 hv = (_Float16)o;
    _Float16 lv = (_Float16)((o - (float)hv) * LO_S);
    if (u < 16) { size_t off = ((size_t)u*T_ + t)*D_ + d; qh[off] = hv; ql[off] = lv; }
    else { size_t off = ((size_t)(u-16)*T_ + t)*D_ + d; kh[off] = hv; kl[off] = lv; }
  } else {
    int kv = u - 24;
    _Float16 hv = (_Float16)val;
    _Float16 lv = (_Float16)((val - (float)hv) * LO_S);
    size_t off = ((size_t)kv*D_ + d)*T_ + t;
    vth[off] = hv; vtl[off] = lv;
  }
}

// ---------------- weight transpose + fp16 convert (optional split), coalesced 64x64 ----------------
// oh[c*R + r] = (half)in[r*C + c]
template<bool SPL>
__global__ __launch_bounds__(256) void transpose_k(const float* __restrict__ in, _Float16* __restrict__ oh,
                                                   _Float16* __restrict__ ol, int R, int C) {
  size_t zo = (size_t)blockIdx.z * R * C;
  in += zo; oh += zo; if (SPL) ol += zo;
  __shared__ float tile[64][68];            // [src_row][src_col], padded
  const int c0 = blockIdx.x*64, r0 = blockIdx.y*64;
  const int tid = threadIdx.x;
  const int lr = tid >> 4;                  // 0..15
  const int lc = (tid & 15) * 4;            // 0..60
  #pragma unroll
  for (int rg = 0; rg < 4; ++rg) {
    float4 v = *(const float4*)(in + (size_t)(r0 + rg*16 + lr)*C + c0 + lc);
    *(float4*)&tile[rg*16 + lr][lc] = v;
  }
  __syncthreads();
  const int orow = tid >> 2;                // 0..63 (output row = source col)
  const int oc   = (tid & 3) * 16;          // 0..48 (offset along r)
  half8 h0v, h1v, l0v, l1v;
  #pragma unroll
  for (int j = 0; j < 16; ++j) {
    float f = tile[oc + j][orow];
    _Float16 h = (_Float16)f;
    if (j < 8) { h0v[j] = h; if (SPL) l0v[j] = (_Float16)((f - (float)h) * LO_S); }
    else       { h1v[j-8] = h; if (SPL) l1v[j-8] = (_Float16)((f - (float)h) * LO_S); }
  }
  const size_t ob = (size_t)(c0 + orow)*R + r0 + oc;
  *(half8*)(oh + ob)     = h0v;
  *(half8*)(oh + ob + 8) = h1v;
  if (SPL) { *(half8*)(ol + ob) = l0v; *(half8*)(ol + ob + 8) = l1v; }
}

// gate/up interleaving transpose: out[2j+p][h] = in[h][j + p*Ih]; coalesced 64h x 32j tiles
__global__ __launch_bounds__(256) void transpose_gu_k(const float* __restrict__ in, _Float16* __restrict__ out,
                                                      int R, int Ih) {
  size_t zi = (size_t)blockIdx.z * R * 2 * Ih;
  in += zi; out += zi;
  __shared__ float tg[64][36], tu[64][36];  // [h][j]
  const int j0 = blockIdx.x*32, h0 = blockIdx.y*64;
  const int tid = threadIdx.x;
  const int lh = tid >> 2;                  // 0..63
  const int lj = (tid & 3) * 8;             // 0..24
  const int C = 2*Ih;
  const float* src = in + (size_t)(h0 + lh)*C + j0 + lj;
  float4 ga = *(const float4*)(src);
  float4 gb = *(const float4*)(src + 4);
  float4 ua = *(const float4*)(src + Ih);
  float4 ub = *(const float4*)(src + Ih + 4);
  *(float4*)&tg[lh][lj]   = ga;
  *(float4*)&tg[lh][lj+4] = gb;
  *(float4*)&tu[lh][lj]   = ua;
  *(float4*)&tu[lh][lj+4] = ub;
  __syncthreads();
  const int oj = tid >> 3;                  // 0..31
  const int p  = (tid >> 2) & 1;
  const int oc = (tid & 3) * 16;            // 0..48
  float (*sel)[36] = p ? tu : tg;
  half8 a, b;
  #pragma unroll
  for (int j = 0; j < 16; ++j) {
    float f = sel[oc + j][oj];
    if (j < 8) a[j] = (_Float16)f; else b[j-8] = (_Float16)f;
  }
  const size_t ob = (size_t)(2*(j0 + oj) + p)*R + h0 + oc;
  *(half8*)(out + ob)     = a;
  *(half8*)(out + ob + 8) = b;
}

// ---------------- flash attention: balanced unpaired tiles, dbuf LDS, defer-max ----------------
__global__ __launch_bounds__(256) void attn_k(
    const _Float16* __restrict__ qh_, const _Float16* __restrict__ ql_,
    const _Float16* __restrict__ kh_, const _Float16* __restrict__ kl_,
    const _Float16* __restrict__ vh_, const _Float16* __restrict__ vl_,
    _Float16* __restrict__ aoh, _Float16* __restrict__ aol) {
  __shared__ _Float16 sK [2][4096];
  __shared__ _Float16 sKl[2][4096];
  __shared__ _Float16 sV [2][4096];
  __shared__ _Float16 sVl[2][4096];
  const int head = blockIdx.x;
  const int y = blockIdx.y;
  const int tile = (y < 16) ? (31 - 2*y) : (2*(y-16));
  const int kvh = head >> 1;
  const int wid = threadIdx.x >> 6, lane = threadIdx.x & 63;
  const int fr = lane & 15, fs = lane >> 4;
  const float scale = 0.08838834764831845f;

  const char* kbC  = (const char*)(kh_ + (size_t)kvh*T_*D_);
  const char* kbCl = (const char*)(kl_ + (size_t)kvh*T_*D_);
  const char* vbC  = (const char*)(vh_ + (size_t)kvh*D_*T_);
  const char* vbCl = (const char*)(vl_ + (size_t)kvh*D_*T_);

  auto stage = [&](int buf, int kvt) {
    #pragma unroll
    for (int i = 0; i < 2; ++i) {
      const int off  = wid*2048 + i*1024;
      const int loff = off + lane*16;
      const int r  = loff >> 8;
      const int u  = (loff >> 4) & 15;
      const int us = u ^ (r & 7);
      const size_t gb = ((size_t)(kvt + r) << 8) + ((size_t)us << 4);
      GL16(kbC  + gb, (char*)&sK [buf][0] + off);
      GL16(kbCl + gb, (char*)&sKl[buf][0] + off);
      const int d   = loff >> 6;
      const int uv  = (loff >> 4) & 3;
      const int uvs = uv ^ ((d >> 2) & 3);
      const size_t gvb = (size_t)d*(T_*2) + (size_t)kvt*2 + ((size_t)uvs << 4);
      GL16(vbC  + gvb, (char*)&sV [buf][0] + off);
      GL16(vbCl + gvb, (char*)&sVl[buf][0] + off);
    }
  };

  const int q0 = tile*64 + wid*16;
  const int qrow = q0 + fr;
  const _Float16* qb_  = qh_ + ((size_t)head*T_ + qrow)*D_;
  const _Float16* qlb_ = ql_ + ((size_t)head*T_ + qrow)*D_;
  half8 qf[4], qfl[4];
  #pragma unroll
  for (int s = 0; s < 4; ++s) {
    qf[s]  = *(const half8*)(qb_  + s*32 + fs*8);
    qfl[s] = *(const half8*)(qlb_ + s*32 + fs*8);
  }
  float m = -1e30f, lsum = 0.f;
  f32x4 oacc[8] = {};
  f32x4 oacc2[8] = {};
  const int nc = 2*tile + 2;

  stage(0, 0);
  #pragma unroll 1
  for (int c = 0; c < nc; ++c) {
    const int kvt = c*32;
    const int buf = c & 1;
    __syncthreads();
    if (c + 1 < nc) stage(buf ^ 1, kvt + 32);

    f32x4 sa = {0,0,0,0}, sa2 = {0,0,0,0}, sb = {0,0,0,0}, sb2 = {0,0,0,0};
    __builtin_amdgcn_s_setprio(1);
    #pragma unroll
    for (int s = 0; s < 4; ++s) {
      const int rA = fr, rB = fr + 16;
      const int eA = (((4*s + fs) ^ (rA & 7)) << 3);
      const int eB = (((4*s + fs) ^ (rB & 7)) << 3);
      half8 kfA  = *(const half8*)&sK [buf][rA*128 + eA];
      half8 kflA = *(const half8*)&sKl[buf][rA*128 + eA];
      half8 kfB  = *(const half8*)&sK [buf][rB*128 + eB];
      half8 kflB = *(const half8*)&sKl[buf][rB*128 + eB];
      sa  = MFMA32(kfA, qf[s], sa);
      sa2 = MFMA32(kfA, qfl[s], sa2);
      sa2 = MFMA32(kflA, qf[s], sa2);
      sb  = MFMA32(kfB, qf[s], sb);
      sb2 = MFMA32(kfB, qfl[s], sb2);
      sb2 = MFMA32(kflB, qf[s], sb2);
    }
    __builtin_amdgcn_s_setprio(0);

    float sv[8];
    #pragma unroll
    for (int r = 0; r < 4; ++r) {
      float xA = (sa[r] + sa2[r]*LO_I) * scale;
      sv[r] = (kvt + fs*4 + r > qrow) ? -INFINITY : xA;
      float xB = (sb[r] + sb2[r]*LO_I) * scale;
      sv[4+r] = (kvt + 16 + fs*4 + r > qrow) ? -INFINITY : xB;
    }
    float tm = -INFINITY;
    #pragma unroll
    for (int j = 0; j < 8; ++j) tm = fmaxf(tm, sv[j]);
    tm = fmaxf(tm, __shfl_xor(tm, 16));
    tm = fmaxf(tm, __shfl_xor(tm, 32));
    if (tm > m + 8.f) {
      float f = __expf(m - tm);
      lsum *= f;
      #pragma unroll
      for (int db = 0; db < 8; ++db) { oacc[db] *= f; oacc2[db] *= f; }
      m = tm;
    }
    float p[8]; float ps = 0.f;
    #pragma unroll
    for (int j = 0; j < 8; ++j) { p[j] = __expf(sv[j] - m); ps += p[j]; }
    ps += __shfl_xor(ps, 16);
    ps += __shfl_xor(ps, 32);
    lsum += ps;
    half8 ph, pl;
    #pragma unroll
    for (int j = 0; j < 8; ++j) {
      _Float16 hp = (_Float16)p[j];
      ph[j] = hp;
      pl[j] = (_Float16)((p[j] - (float)hp) * LO_S);
    }

    __builtin_amdgcn_s_setprio(1);
    #pragma unroll
    for (int db = 0; db < 8; ++db) {
      const int d0 = db*16 + fr;
      const int base = d0*32;
      const int sw = (d0 >> 2) & 3;
      const int e1 = ((((fs>>1)    ) ^ sw) << 3) + (fs & 1)*4;
      const int e2 = (((2 + (fs>>1)) ^ sw) << 3) + (fs & 1)*4;
      half4_t v0  = *(const half4_t*)&sV [buf][base + e1];
      half4_t v1  = *(const half4_t*)&sV [buf][base + e2];
      half4_t v0l = *(const half4_t*)&sVl[buf][base + e1];
      half4_t v1l = *(const half4_t*)&sVl[buf][base + e2];
      half8 vf, vfl;
      #pragma unroll
      for (int j = 0; j < 4; ++j) { vf[j] = v0[j]; vf[4+j] = v1[j]; vfl[j] = v0l[j]; vfl[4+j] = v1l[j]; }
      oacc[db]  = MFMA32(vf, ph, oacc[db]);
      oacc2[db] = MFMA32(vf, pl, oacc2[db]);
      oacc2[db] = MFMA32(vfl, ph, oacc2[db]);
    }
    __builtin_amdgcn_s_setprio(0);
  }

  float inv = 1.0f / lsum;
  #pragma unroll
  for (int db = 0; db < 8; ++db) {
    #pragma unroll
    for (int r = 0; r < 4; ++r) {
      float val = (oacc[db][r] + oacc2[db][r]*LO_I) * inv;
      int dd = db*16 + fs*4 + r;
      size_t off = (size_t)qrow*(NH_*D_) + head*D_ + dd;
      _Float16 hv = (_Float16)val;
      aoh[off] = hv;
      aol[off] = (_Float16)((val - (float)hv) * LO_S);
    }
  }
}

// ---------------- router: fp32 logits, sigmoid, top-4, dispatch lists ----------------
__global__ __launch_bounds__(256) void router_k(const _Float16* __restrict__ x2h, const _Float16* __restrict__ x2l,
    const float* __restrict__ gw, const float* __restrict__ eb,
    int* __restrict__ cnt, int* __restrict__ list, float* __restrict__ wl) {
  int t = blockIdx.x*4 + (threadIdx.x >> 6);
  int lane = threadIdx.x & 63;
  const _Float16* xh = x2h + (size_t)t*H_;
  const _Float16* xl = x2l + (size_t)t*H_;
  f32x4 a0 = {0,0,0,0}, a1 = {0,0,0,0}, a2 = {0,0,0,0}, a3 = {0,0,0,0};
  for (int h = lane; h < H_; h += 64) {
    float xv = (float)xh[h] + (float)xl[h] * LO_I;
    const float* g = gw + (size_t)h*16;
    a0 += xv * (*(const f32x4*)(g));
    a1 += xv * (*(const f32x4*)(g+4));
    a2 += xv * (*(const f32x4*)(g+8));
    a3 += xv * (*(const f32x4*)(g+12));
  }
  float acc[16];
  #pragma unroll
  for (int j = 0; j < 4; ++j) { acc[j]=a0[j]; acc[4+j]=a1[j]; acc[8+j]=a2[j]; acc[12+j]=a3[j]; }
  #pragma unroll
  for (int mm = 1; mm < 64; mm <<= 1) {
    #pragma unroll
    for (int e2 = 0; e2 < 16; ++e2) acc[e2] += __shfl_xor(acc[e2], mm);
  }
  if (lane == 0) {
    float sig[16], biased[16];
    #pragma unroll
    for (int e2 = 0; e2 < 16; ++e2) {
      float s = 1.0f / (1.0f + expf(-acc[e2]));
      sig[e2] = s; biased[e2] = s + eb[e2];
    }
    int sel[4]; float wv[4]; float wsum = 0.f;
    unsigned used = 0;
    for (int j = 0; j < 4; ++j) {
      int bi = -1; float bv = -1e30f;
      for (int e2 = 0; e2 < 16; ++e2)
        if (!((used >> e2) & 1) && biased[e2] > bv) { bv = biased[e2]; bi = e2; }
      used |= 1u << bi;
      sel[j] = bi; wv[j] = sig[bi]; wsum += sig[bi];
    }
    for (int j = 0; j < 4; ++j) {
      int e2 = sel[j];
      int pos = atomicAdd(&cnt[e2], 1);
      list[e2*T_ + pos] = t;
      wl[e2*T_ + pos] = wv[j] / wsum;
    }
  }
}

__global__ void scan_k(const int* __restrict__ cnt, int* __restrict__ base) {
  if (threadIdx.x == 0 && blockIdx.x == 0) {
    int s = 0;
    for (int e2 = 0; e2 < 16; ++e2) { base[e2] = s; s += cnt[e2]; }
  }
}

// ---------------- GEMM args ----------------
struct GArgs {
  const _Float16* Ah; const _Float16* Al;
  const _Float16* Bh; const _Float16* Bl;
  int M, N, K;
  const int* rowlist; const float* wlist; const int* cnt; const int* base;
  float* C; const float* res; _Float16* act; float* outAt; int ldc;
};

// ---------------- 128x128 GEMM: 512 threads (8 waves, 2x4), counted-vmcnt pipeline ----------------
template<int MODE, bool SPLIT, int DEPTH>
__global__ __launch_bounds__(512, 4) void gemm_k(GArgs p) {
  constexpr int LPS = SPLIT ? 4 : 2;   // loads per stage per thread (1 per tensor)
  const int e = blockIdx.z;
  const int M = p.cnt ? p.cnt[e] : p.M;
  const int m0 = blockIdx.y * 128;
  if (m0 >= M) return;
  const int n0 = blockIdx.x * 128;
  const int tid = threadIdx.x;
  const int wid = tid >> 6, lane = tid & 63;

  __shared__ _Float16 sA[DEPTH][4096];
  __shared__ _Float16 sB[DEPTH][4096];
  __shared__ _Float16 sAl[SPLIT ? DEPTH : 1][SPLIT ? 4096 : 8];
  __shared__ _Float16 sBl[SPLIT ? DEPTH : 1][SPLIT ? 4096 : 8];

  const int srow = tid >> 2;
  const int slot = ((tid & 3) ^ (srow & 3)) * 16;
  const int ldsOff = wid * 1024;
  size_t aIdx;
  if constexpr (MODE == 2) {
    if (p.rowlist) {
      int tok = p.rowlist[(size_t)e * T_ + m0 + srow];
      tok = tok < 0 ? 0 : (tok > T_ - 1 ? T_ - 1 : tok);
      aIdx = (size_t)tok;
    } else aIdx = (size_t)(m0 + srow);
  } else if constexpr (MODE == 3) {
    aIdx = (size_t)p.base[e] + m0 + srow;
  } else {
    aIdx = (size_t)(m0 + srow);
  }
  const char* aPtr  = (const char*)(p.Ah + aIdx * (size_t)p.K) + slot;
  const char* alPtr = SPLIT ? (const char*)(p.Al + aIdx * (size_t)p.K) + slot : aPtr;
  const size_t bIdx = (size_t)e * p.N + n0 + srow;
  const char* bPtr  = (const char*)(p.Bh + bIdx * (size_t)p.K) + slot;
  const char* blPtr = SPLIT ? (const char*)(p.Bl + bIdx * (size_t)p.K) + slot : bPtr;

  auto stage = [&](int buf, int kb) {
    GL16(aPtr + kb, (char*)&sA[buf][0] + ldsOff);
    GL16(bPtr + kb, (char*)&sB[buf][0] + ldsOff);
    if constexpr (SPLIT) {
      GL16(alPtr + kb, (char*)&sAl[buf][0] + ldsOff);
      GL16(blPtr + kb, (char*)&sBl[buf][0] + ldsOff);
    }
  };

  const int wr = (wid >> 2) * 64, wc = (wid & 3) * 32;
  const int fr = lane & 15, fs = lane >> 4;

  f32x4 acc[4][2] = {};
  f32x4 acc2[4][2] = {};

  const int nt = p.K >> 5;
  stage(0, 0);
  if constexpr (DEPTH == 3) { if (nt > 1) stage(1, 64); }

  for (int t = 0; t < nt; ++t) {
    if constexpr (DEPTH == 3) {
      if (t + 2 < nt) stage((t + 2) % 3, (t + 2) * 64);
      __builtin_amdgcn_sched_barrier(0);
      if (t + 2 < nt)      asm volatile("s_waitcnt vmcnt(%0)" :: "i"(2*LPS) : "memory");
      else if (t + 1 < nt) asm volatile("s_waitcnt vmcnt(%0)" :: "i"(LPS)   : "memory");
      else                 asm volatile("s_waitcnt vmcnt(0)" ::: "memory");
    } else {
      if (t + 1 < nt) {
        stage((t + 1) & 1, (t + 1) * 64);
        __builtin_amdgcn_sched_barrier(0);
        asm volatile("s_waitcnt vmcnt(%0)" :: "i"(LPS) : "memory");
      } else {
        __builtin_amdgcn_sched_barrier(0);
        asm volatile("s_waitcnt vmcnt(0)" ::: "memory");
      }
    }
    __builtin_amdgcn_s_barrier();
    __builtin_amdgcn_sched_barrier(0);

    const int cb = (DEPTH == 3) ? (t % 3) : (t & 1);
    half8 ah[4], bh[2], al[4], bl[2];
    #pragma unroll
    for (int i = 0; i < 4; ++i) {
      const int pa = (fs ^ ((wr + i*16 + fr) & 3)) * 8;
      ah[i] = *(const half8*)&sA[cb][(wr + i*16 + fr)*32 + pa];
      if constexpr (SPLIT) al[i] = *(const half8*)&sAl[cb][(wr + i*16 + fr)*32 + pa];
    }
    #pragma unroll
    for (int i = 0; i < 2; ++i) {
      const int pb = (fs ^ ((wc + i*16 + fr) & 3)) * 8;
      bh[i] = *(const half8*)&sB[cb][(wc + i*16 + fr)*32 + pb];
      if constexpr (SPLIT) bl[i] = *(const half8*)&sBl[cb][(wc + i*16 + fr)*32 + pb];
    }
    __builtin_amdgcn_s_setprio(1);
    #pragma unroll
    for (int mi = 0; mi < 4; ++mi) {
      #pragma unroll
      for (int ni = 0; ni < 2; ++ni) {
        acc[mi][ni] = MFMA32(ah[mi], bh[ni], acc[mi][ni]);
        if constexpr (SPLIT) {
          acc2[mi][ni] = MFMA32(ah[mi], bl[ni], acc2[mi][ni]);
          acc2[mi][ni] = MFMA32(al[mi], bh[ni], acc2[mi][ni]);
        }
      }
    }
    __builtin_amdgcn_s_setprio(0);
    __builtin_amdgcn_sched_barrier(0);
    __builtin_amdgcn_s_barrier();
    __builtin_amdgcn_sched_barrier(0);
  }

  const int actld = p.N >> 1;
  #pragma unroll
  for (int mi = 0; mi < 4; ++mi) {
    #pragma unroll
    for (int ni = 0; ni < 2; ++ni) {
      f32x4 v4 = acc[mi][ni];
      if constexpr (SPLIT) v4 = v4 + acc2[mi][ni] * LO_I;
      const int colb = n0 + wc + ni*16 + fr;
      #pragma unroll
      for (int r = 0; r < 4; ++r) {
        const int row = m0 + wr + mi*16 + fs*4 + r;
        float val = v4[r];
        if constexpr (MODE == 0) {
          if (row < M) p.C[(size_t)row * p.ldc + colb] = val;
        } else if constexpr (MODE == 1) {
          if (row < M) p.C[(size_t)row * p.ldc + colb] = p.res[(size_t)row * p.ldc + colb] + val;
        } else if constexpr (MODE == 2) {
          float other = __shfl_xor(val, 1);
          float g = (fr & 1) ? other : val;
          float u = (fr & 1) ? val : other;
          float a = g / (1.0f + __expf(-g)) * u;
          if (!(fr & 1) && row < M) {
            size_t ar = (size_t)(p.base ? p.base[e] : 0) + row;
            p.act[ar * (size_t)actld + (colb >> 1)] = (_Float16)a;
          }
        } else {
          if (row < M) {
            int tok = p.rowlist[(size_t)e * T_ + row];
            float w = p.wlist[(size_t)e * T_ + row];
            atomicAdd(&p.outAt[(size_t)tok * p.ldc + colb], val * w);
          }
        }
      }
    }
  }
}

// ---------------- launcher ----------------
extern "C" void kernel_launch(void* const* d_in, const int* in_sizes, int n_in,
                              void* d_out, int out_size, void* d_ws, size_t ws_size,
                              hipStream_t stream) {
  (void)in_sizes; (void)n_in; (void)out_size; (void)ws_size;
  const int*   positions = (const int*)  d_in[0];
  const float* hidden    = (const float*)d_in[1];
  const float* qkv_w     = (const float*)d_in[2];
  const float* o_w       = (const float*)d_in[3];
  const float* q_norm_w  = (const float*)d_in[4];
  const float* k_norm_w  = (const float*)d_in[5];
  const float* ln1_w     = (const float*)d_in[6];
  const float* ln2_w     = (const float*)d_in[7];
  const float* gate_w    = (const float*)d_in[8];
  const float* ebias     = (const float*)d_in[9];
  const float* sgu_w     = (const float*)d_in[10];
  const float* sdown_w   = (const float*)d_in[11];
  const float* egu_w     = (const float*)d_in[12];
  const float* edown_w   = (const float*)d_in[13];
  float* out = (float*)d_out;

  char* wsp = (char*)d_ws;
  size_t off = 0;
  auto alloc = [&](size_t bytes) -> void* {
    void* p = wsp + off;
    off = (off + bytes + 255) & ~(size_t)255;
    return p;
  };
  float*    cosT   = (float*)   alloc((size_t)T_*64*4);
  float*    sinT   = (float*)   alloc((size_t)T_*64*4);
  _Float16* x_h    = (_Float16*)alloc((size_t)T_*H_*2);
  _Float16* x_l    = (_Float16*)alloc((size_t)T_*H_*2);
  float*    qkvb   = (float*)   alloc((size_t)T_*4096*4);
  _Float16* q_h    = (_Float16*)alloc((size_t)NH_*T_*D_*2);
  _Float16* q_l    = (_Float16*)alloc((size_t)NH_*T_*D_*2);
  _Float16* k_h    = (_Float16*)alloc((size_t)NKV_*T_*D_*2);
  _Float16* k_l    = (_Float16*)alloc((size_t)NKV_*T_*D_*2);
  _Float16* vt_h   = (_Float16*)alloc((size_t)NKV_*T_*D_*2);
  _Float16* vt_l   = (_Float16*)alloc((size_t)NKV_*T_*D_*2);
  _Float16* ao_h   = (_Float16*)alloc((size_t)T_*NH_*D_*2);
  _Float16* ao_l   = (_Float16*)alloc((size_t)T_*NH_*D_*2);
  float*    hbuf   = (float*)   alloc((size_t)T_*H_*4);
  _Float16* x2_h   = (_Float16*)alloc((size_t)T_*H_*2);
  _Float16* x2_l   = (_Float16*)alloc((size_t)T_*H_*2);
  _Float16* qkvwT_h= (_Float16*)alloc((size_t)4096*H_*2);
  _Float16* qkvwT_l= (_Float16*)alloc((size_t)4096*H_*2);
  _Float16* owT_h  = (_Float16*)alloc((size_t)H_*H_*2);
  _Float16* owT_l  = (_Float16*)alloc((size_t)H_*H_*2);
  _Float16* sguT   = (_Float16*)alloc((size_t)2*SI_*H_*2);
  _Float16* sdownT = (_Float16*)alloc((size_t)H_*SI_*2);
  _Float16* eguT   = (_Float16*)alloc((size_t)E_*2*I_*H_*2);
  _Float16* edownT = (_Float16*)alloc((size_t)E_*H_*I_*2);
  _Float16* act_s  = (_Float16*)alloc((size_t)T_*SI_*2);
  _Float16* act_e  = (_Float16*)alloc((size_t)(T_*4 + 512)*I_*2);
  int*   cnt   = (int*)  alloc(E_*4);
  int*   ebase = (int*)  alloc(E_*4);
  int*   list  = (int*)  alloc((size_t)E_*T_*4);
  float* wlst  = (float*)alloc((size_t)E_*T_*4);

  hipMemsetAsync(cnt, 0, E_*4, stream);
  tables_k<<<T_, 64, 0, stream>>>(positions, cosT, sinT);

  transpose_k<true ><<<dim3(4096/64, H_/64, 1), 256, 0, stream>>>(qkv_w, qkvwT_h, qkvwT_l, H_, 4096);
  transpose_k<true ><<<dim3(H_/64,  H_/64, 1), 256, 0, stream>>>(o_w, owT_h, owT_l, H_, H_);
  transpose_gu_k    <<<dim3(SI_/32, H_/64, 1), 256, 0, stream>>>(sgu_w, sguT, H_, SI_);
  transpose_k<false><<<dim3(H_/64, SI_/64, 1), 256, 0, stream>>>(sdown_w, sdownT, nullptr, SI_, H_);
  transpose_gu_k    <<<dim3(I_/32,  H_/64, E_), 256, 0, stream>>>(egu_w, eguT, H_, I_);
  transpose_k<false><<<dim3(H_/64,  I_/64, E_), 256, 0, stream>>>(edown_w, edownT, nullptr, I_, H_);

  rmsnorm_k<<<T_, 256, 0, stream>>>(hidden, ln1_w, x_h, x_l);

  { GArgs g{}; g.Ah=x_h; g.Al=x_l; g.Bh=qkvwT_h; g.Bl=qkvwT_l; g.M=T_; g.N=4096; g.K=H_;
    g.C=qkvb; g.ldc=4096;
    gemm_k<0,true,2><<<dim3(4096/128, T_/128, 1), 512, 0, stream>>>(g); }

  qkvpost_k<<<dim3(T_, 32, 1), 128, 0, stream>>>(qkvb, q_norm_w, k_norm_w, cosT, sinT,
                                                 q_h, q_l, k_h, k_l, vt_h, vt_l);

  attn_k<<<dim3(NH_, 32), 256, 0, stream>>>(q_h, q_l, k_h, k_l, vt_h, vt_l, ao_h, ao_l);

  { GArgs g{}; g.Ah=ao_h; g.Al=ao_l; g.Bh=owT_h; g.Bl=owT_l; g.M=T_; g.N=H_; g.K=H_;
    g.C=hbuf; g.res=hidden; g.ldc=H_;
    gemm_k<1,true,2><<<dim3(H_/128, T_/128, 1), 512, 0, stream>>>(g); }

  rmsnorm_k<<<T_, 256, 0, stream>>>(hbuf, ln2_w, x2_h, x2_l);

  router_k<<<T_/4, 256, 0, stream>>>(x2_h, x2_l, gate_w, ebias, cnt, list, wlst);
  scan_k<<<1, 64, 0, stream>>>(cnt, ebase);

  { GArgs g{}; g.Ah=x2_h; g.Bh=sguT; g.M=T_; g.N=2*SI_; g.K=H_; g.act=act_s;
    gemm_k<2,false,3><<<dim3(2*SI_/128, T_/128, 1), 512, 0, stream>>>(g); }

  { GArgs g{}; g.Ah=act_s; g.Bh=sdownT; g.M=T_; g.N=H_; g.K=SI_;
    g.C=out; g.res=hbuf; g.ldc=H_;
    gemm_k<1,false,3><<<dim3(H_/128, T_/128, 1), 512, 0, stream>>>(g); }

  { GArgs g{}; g.Ah=x2_h; g.Bh=eguT; g.M=T_; g.N=2*I_; g.K=H_;
    g.rowlist=list; g.cnt=cnt; g.base=ebase; g.act=act_e;
    gemm_k<2,false,3><<<dim3(2*I_/128, T_/128, E_), 512, 0, stream>>>(g); }

  { GArgs g{}; g.Ah=act_e; g.Bh=edownT; g.M=T_; g.N=H_; g.K=I_;
    g.rowlist=list; g.wlist=wlst; g.cnt=cnt; g.base=ebase;
    g.outAt=out; g.ldc=H_;
    gemm_k<3,false,3><<<dim3(H_/128, T_/128, E_), 512, 0, stream>>>(g); }
}

// Round 13
// 978.513 us; speedup vs baseline: 1.0534x; 1.0167x over previous
//
#include <hip/hip_runtime.h>
#include <math.h>

#define T_ 2048
#define H_ 2048
#define NH_ 16
#define NKV_ 8
#define D_ 128
#define E_ 16
#define I_ 1024
#define SI_ 1024

typedef _Float16 half8 __attribute__((ext_vector_type(8)));
typedef _Float16 half4_t __attribute__((ext_vector_type(4)));
typedef float f32x4 __attribute__((ext_vector_type(4)));

#define MFMA32(a,b,c) __builtin_amdgcn_mfma_f32_16x16x32_f16((a),(b),(c),0,0,0)

__device__ __constant__ float LO_S = 2048.0f;
__device__ __constant__ float LO_I = 1.0f/2048.0f;
#define EPS_ 1e-5f

#define GL16(gp, lp) __builtin_amdgcn_global_load_lds( \
    (const __attribute__((address_space(1))) unsigned int*)(const void*)(gp), \
    (__attribute__((address_space(3))) unsigned int*)(void*)(lp), 16, 0, 0)

// ---------------- RoPE tables (fp64 for bit-faithful inv_freq) ----------------
__global__ void tables_k(const int* __restrict__ pos, float* __restrict__ cosT, float* __restrict__ sinT) {
  int t = blockIdx.x;
  int j = threadIdx.x; // 0..63
  float pf = (float)pow(10000.0, (double)j / 64.0);
  float invf = 1.0f / pf;
  float ang = (float)pos[t] * invf;
  cosT[t*64 + j] = (float)cos((double)ang);
  sinT[t*64 + j] = (float)sin((double)ang);
}

// ---------------- RMSNorm -> fp16 hi/lo pair ----------------
__global__ __launch_bounds__(256) void rmsnorm_k(const float* __restrict__ x, const float* __restrict__ w,
                                                 _Float16* __restrict__ oh, _Float16* __restrict__ ol) {
  int row = blockIdx.x;
  const float* xr = x + (size_t)row * H_;
  int tid = threadIdx.x;
  float4 a = *(const float4*)(xr + tid*8);
  float4 b = *(const float4*)(xr + tid*8 + 4);
  float ss = a.x*a.x + a.y*a.y + a.z*a.z + a.w*a.w + b.x*b.x + b.y*b.y + b.z*b.z + b.w*b.w;
  #pragma unroll
  for (int m = 1; m < 64; m <<= 1) ss += __shfl_xor(ss, m);
  __shared__ float wsum[4];
  int wid = tid >> 6, lane = tid & 63;
  if (lane == 0) wsum[wid] = ss;
  __syncthreads();
  float tot = wsum[0] + wsum[1] + wsum[2] + wsum[3];
  float rinv = 1.0f / sqrtf(tot / (float)H_ + EPS_);
  const float* av = (const float*)&a;
  const float* bv = (const float*)&b;
  #pragma unroll
  for (int j = 0; j < 8; ++j) {
    float xv = (j < 4) ? av[j] : bv[j-4];
    float val = xv * rinv * w[tid*8 + j];
    _Float16 h = (_Float16)val;
    size_t o = (size_t)row*H_ + tid*8 + j;
    oh[o] = h;
    ol[o] = (_Float16)((val - (float)h) * LO_S);
  }
}

// ---------------- QKV postprocess: ONE block per token (was 32 blocks/token) ----------------
// wave handles slice u = it*4+wid; lane holds d=lane and d=lane+64 -> wave-local rmsnorm + in-register rope.
__global__ __launch_bounds__(256) void qkvpost_k(
    const float* __restrict__ qkv, const float* __restrict__ qnw, const float* __restrict__ knw,
    const float* __restrict__ cosT, const float* __restrict__ sinT,
    _Float16* __restrict__ qh, _Float16* __restrict__ ql,
    _Float16* __restrict__ kh, _Float16* __restrict__ kl,
    _Float16* __restrict__ vth, _Float16* __restrict__ vtl) {
  const int t = blockIdx.x;
  const int wid = threadIdx.x >> 6, lane = threadIdx.x & 63;
  const float* src = qkv + (size_t)t*4096;
  const float c = cosT[t*64 + lane];
  const float s = sinT[t*64 + lane];
  #pragma unroll
  for (int it = 0; it < 8; ++it) {
    const int u = it*4 + wid;
    float x1 = src[u*128 + lane];
    float x2 = src[u*128 + 64 + lane];
    if (u < 24) {
      float ss = x1*x1 + x2*x2;
      #pragma unroll
      for (int m = 1; m < 64; m <<= 1) ss += __shfl_xor(ss, m);
      float rinv = 1.0f / sqrtf(ss / 128.0f + EPS_);
      const float* nw = (u < 16) ? qnw : knw;
      float n1 = x1 * rinv * nw[lane];
      float n2 = x2 * rinv * nw[lane + 64];
      float o1 = n1*c - n2*s;
      float o2 = n2*c + n1*s;
      _Float16 h1 = (_Float16)o1, h2 = (_Float16)o2;
      _Float16 l1 = (_Float16)((o1 - (float)h1) * LO_S);
      _Float16 l2 = (_Float16)((o2 - (float)h2) * LO_S);
      if (u < 16) {
        size_t off = ((size_t)u*T_ + t)*D_;
        qh[off + lane] = h1; qh[off + 64 + lane] = h2;
        ql[off + lane] = l1; ql[off + 64 + lane] = l2;
      } else {
        size_t off = ((size_t)(u-16)*T_ + t)*D_;
        kh[off + lane] = h1; kh[off + 64 + lane] = h2;
        kl[off + lane] = l1; kl[off + 64 + lane] = l2;
      }
    } else {
      const int kv = u - 24;
      _Float16 h1 = (_Float16)x1, h2 = (_Float16)x2;
      _Float16 l1 = (_Float16)((x1 - (float)h1) * LO_S);
      _Float16 l2 = (_Float16)((x2 - (float)h2) * LO_S);
      size_t o1 = ((size_t)kv*D_ + lane)*T_ + t;
      size_t o2 = ((size_t)kv*D_ + 64 + lane)*T_ + t;
      vth[o1] = h1; vth[o2] = h2;
      vtl[o1] = l1; vtl[o2] = l2;
    }
  }
}

// ---------------- weight transpose + fp16 convert (optional split), coalesced 64x64 ----------------
template<bool SPL>
__global__ __launch_bounds__(256) void transpose_k(const float* __restrict__ in, _Float16* __restrict__ oh,
                                                   _Float16* __restrict__ ol, int R, int C) {
  size_t zo = (size_t)blockIdx.z * R * C;
  in += zo; oh += zo; if (SPL) ol += zo;
  __shared__ float tile[64][68];
  const int c0 = blockIdx.x*64, r0 = blockIdx.y*64;
  const int tid = threadIdx.x;
  const int lr = tid >> 4;
  const int lc = (tid & 15) * 4;
  #pragma unroll
  for (int rg = 0; rg < 4; ++rg) {
    float4 v = *(const float4*)(in + (size_t)(r0 + rg*16 + lr)*C + c0 + lc);
    *(float4*)&tile[rg*16 + lr][lc] = v;
  }
  __syncthreads();
  const int orow = tid >> 2;
  const int oc   = (tid & 3) * 16;
  half8 h0v, h1v, l0v, l1v;
  #pragma unroll
  for (int j = 0; j < 16; ++j) {
    float f = tile[oc + j][orow];
    _Float16 h = (_Float16)f;
    if (j < 8) { h0v[j] = h; if (SPL) l0v[j] = (_Float16)((f - (float)h) * LO_S); }
    else       { h1v[j-8] = h; if (SPL) l1v[j-8] = (_Float16)((f - (float)h) * LO_S); }
  }
  const size_t ob = (size_t)(c0 + orow)*R + r0 + oc;
  *(half8*)(oh + ob)     = h0v;
  *(half8*)(oh + ob + 8) = h1v;
  if (SPL) { *(half8*)(ol + ob) = l0v; *(half8*)(ol + ob + 8) = l1v; }
}

// gate/up interleaving transpose: out[2j+p][h] = in[h][j + p*Ih]; coalesced 64h x 32j tiles
__global__ __launch_bounds__(256) void transpose_gu_k(const float* __restrict__ in, _Float16* __restrict__ out,
                                                      int R, int Ih) {
  size_t zi = (size_t)blockIdx.z * R * 2 * Ih;
  in += zi; out += zi;
  __shared__ float tg[64][36], tu[64][36];
  const int j0 = blockIdx.x*32, h0 = blockIdx.y*64;
  const int tid = threadIdx.x;
  const int lh = tid >> 2;
  const int lj = (tid & 3) * 8;
  const int C = 2*Ih;
  const float* src = in + (size_t)(h0 + lh)*C + j0 + lj;
  float4 ga = *(const float4*)(src);
  float4 gb = *(const float4*)(src + 4);
  float4 ua = *(const float4*)(src + Ih);
  float4 ub = *(const float4*)(src + Ih + 4);
  *(float4*)&tg[lh][lj]   = ga;
  *(float4*)&tg[lh][lj+4] = gb;
  *(float4*)&tu[lh][lj]   = ua;
  *(float4*)&tu[lh][lj+4] = ub;
  __syncthreads();
  const int oj = tid >> 3;
  const int p  = (tid >> 2) & 1;
  const int oc = (tid & 3) * 16;
  float (*sel)[36] = p ? tu : tg;
  half8 a, b;
  #pragma unroll
  for (int j = 0; j < 16; ++j) {
    float f = sel[oc + j][oj];
    if (j < 8) a[j] = (_Float16)f; else b[j-8] = (_Float16)f;
  }
  const size_t ob = (size_t)(2*(j0 + oj) + p)*R + h0 + oc;
  *(half8*)(out + ob)     = a;
  *(half8*)(out + ob + 8) = b;
}

// ---------------- flash attention: balanced unpaired tiles, dbuf LDS, defer-max ----------------
__global__ __launch_bounds__(256) void attn_k(
    const _Float16* __restrict__ qh_, const _Float16* __restrict__ ql_,
    const _Float16* __restrict__ kh_, const _Float16* __restrict__ kl_,
    const _Float16* __restrict__ vh_, const _Float16* __restrict__ vl_,
    _Float16* __restrict__ aoh, _Float16* __restrict__ aol) {
  __shared__ _Float16 sK [2][4096];
  __shared__ _Float16 sKl[2][4096];
  __shared__ _Float16 sV [2][4096];
  __shared__ _Float16 sVl[2][4096];
  const int head = blockIdx.x;
  const int y = blockIdx.y;
  const int tile = (y < 16) ? (31 - 2*y) : (2*(y-16));
  const int kvh = head >> 1;
  const int wid = threadIdx.x >> 6, lane = threadIdx.x & 63;
  const int fr = lane & 15, fs = lane >> 4;
  const float scale = 0.08838834764831845f;

  const char* kbC  = (const char*)(kh_ + (size_t)kvh*T_*D_);
  const char* kbCl = (const char*)(kl_ + (size_t)kvh*T_*D_);
  const char* vbC  = (const char*)(vh_ + (size_t)kvh*D_*T_);
  const char* vbCl = (const char*)(vl_ + (size_t)kvh*D_*T_);

  auto stage = [&](int buf, int kvt) {
    #pragma unroll
    for (int i = 0; i < 2; ++i) {
      const int off  = wid*2048 + i*1024;
      const int loff = off + lane*16;
      const int r  = loff >> 8;
      const int u  = (loff >> 4) & 15;
      const int us = u ^ (r & 7);
      const size_t gb = ((size_t)(kvt + r) << 8) + ((size_t)us << 4);
      GL16(kbC  + gb, (char*)&sK [buf][0] + off);
      GL16(kbCl + gb, (char*)&sKl[buf][0] + off);
      const int d   = loff >> 6;
      const int uv  = (loff >> 4) & 3;
      const int uvs = uv ^ ((d >> 2) & 3);
      const size_t gvb = (size_t)d*(T_*2) + (size_t)kvt*2 + ((size_t)uvs << 4);
      GL16(vbC  + gvb, (char*)&sV [buf][0] + off);
      GL16(vbCl + gvb, (char*)&sVl[buf][0] + off);
    }
  };

  const int q0 = tile*64 + wid*16;
  const int qrow = q0 + fr;
  const _Float16* qb_  = qh_ + ((size_t)head*T_ + qrow)*D_;
  const _Float16* qlb_ = ql_ + ((size_t)head*T_ + qrow)*D_;
  half8 qf[4], qfl[4];
  #pragma unroll
  for (int s = 0; s < 4; ++s) {
    qf[s]  = *(const half8*)(qb_  + s*32 + fs*8);
    qfl[s] = *(const half8*)(qlb_ + s*32 + fs*8);
  }
  float m = -1e30f, lsum = 0.f;
  f32x4 oacc[8] = {};
  f32x4 oacc2[8] = {};
  const int nc = 2*tile + 2;

  stage(0, 0);
  #pragma unroll 1
  for (int c = 0; c < nc; ++c) {
    const int kvt = c*32;
    const int buf = c & 1;
    __syncthreads();
    if (c + 1 < nc) stage(buf ^ 1, kvt + 32);

    f32x4 sa = {0,0,0,0}, sa2 = {0,0,0,0}, sb = {0,0,0,0}, sb2 = {0,0,0,0};
    __builtin_amdgcn_s_setprio(1);
    #pragma unroll
    for (int s = 0; s < 4; ++s) {
      const int rA = fr, rB = fr + 16;
      const int eA = (((4*s + fs) ^ (rA & 7)) << 3);
      const int eB = (((4*s + fs) ^ (rB & 7)) << 3);
      half8 kfA  = *(const half8*)&sK [buf][rA*128 + eA];
      half8 kflA = *(const half8*)&sKl[buf][rA*128 + eA];
      half8 kfB  = *(const half8*)&sK [buf][rB*128 + eB];
      half8 kflB = *(const half8*)&sKl[buf][rB*128 + eB];
      sa  = MFMA32(kfA, qf[s], sa);
      sa2 = MFMA32(kfA, qfl[s], sa2);
      sa2 = MFMA32(kflA, qf[s], sa2);
      sb  = MFMA32(kfB, qf[s], sb);
      sb2 = MFMA32(kfB, qfl[s], sb2);
      sb2 = MFMA32(kflB, qf[s], sb2);
    }
    __builtin_amdgcn_s_setprio(0);

    float sv[8];
    #pragma unroll
    for (int r = 0; r < 4; ++r) {
      float xA = (sa[r] + sa2[r]*LO_I) * scale;
      sv[r] = (kvt + fs*4 + r > qrow) ? -INFINITY : xA;
      float xB = (sb[r] + sb2[r]*LO_I) * scale;
      sv[4+r] = (kvt + 16 + fs*4 + r > qrow) ? -INFINITY : xB;
    }
    float tm = -INFINITY;
    #pragma unroll
    for (int j = 0; j < 8; ++j) tm = fmaxf(tm, sv[j]);
    tm = fmaxf(tm, __shfl_xor(tm, 16));
    tm = fmaxf(tm, __shfl_xor(tm, 32));
    if (tm > m + 8.f) {
      float f = __expf(m - tm);
      lsum *= f;
      #pragma unroll
      for (int db = 0; db < 8; ++db) { oacc[db] *= f; oacc2[db] *= f; }
      m = tm;
    }
    float p[8]; float ps = 0.f;
    #pragma unroll
    for (int j = 0; j < 8; ++j) { p[j] = __expf(sv[j] - m); ps += p[j]; }
    ps += __shfl_xor(ps, 16);
    ps += __shfl_xor(ps, 32);
    lsum += ps;
    half8 ph, pl;
    #pragma unroll
    for (int j = 0; j < 8; ++j) {
      _Float16 hp = (_Float16)p[j];
      ph[j] = hp;
      pl[j] = (_Float16)((p[j] - (float)hp) * LO_S);
    }

    __builtin_amdgcn_s_setprio(1);
    #pragma unroll
    for (int db = 0; db < 8; ++db) {
      const int d0 = db*16 + fr;
      const int base = d0*32;
      const int sw = (d0 >> 2) & 3;
      const int e1 = ((((fs>>1)    ) ^ sw) << 3) + (fs & 1)*4;
      const int e2 = (((2 + (fs>>1)) ^ sw) << 3) + (fs & 1)*4;
      half4_t v0  = *(const half4_t*)&sV [buf][base + e1];
      half4_t v1  = *(const half4_t*)&sV [buf][base + e2];
      half4_t v0l = *(const half4_t*)&sVl[buf][base + e1];
      half4_t v1l = *(const half4_t*)&sVl[buf][base + e2];
      half8 vf, vfl;
      #pragma unroll
      for (int j = 0; j < 4; ++j) { vf[j] = v0[j]; vf[4+j] = v1[j]; vfl[j] = v0l[j]; vfl[4+j] = v1l[j]; }
      oacc[db]  = MFMA32(vf, ph, oacc[db]);
      oacc2[db] = MFMA32(vf, pl, oacc2[db]);
      oacc2[db] = MFMA32(vfl, ph, oacc2[db]);
    }
    __builtin_amdgcn_s_setprio(0);
  }

  float inv = 1.0f / lsum;
  #pragma unroll
  for (int db = 0; db < 8; ++db) {
    #pragma unroll
    for (int r = 0; r < 4; ++r) {
      float val = (oacc[db][r] + oacc2[db][r]*LO_I) * inv;
      int dd = db*16 + fs*4 + r;
      size_t off = (size_t)qrow*(NH_*D_) + head*D_ + dd;
      _Float16 hv = (_Float16)val;
      aoh[off] = hv;
      aol[off] = (_Float16)((val - (float)hv) * LO_S);
    }
  }
}

// ---------------- router: fp32 logits, sigmoid, top-4, dispatch lists + token->slot map ----------------
__global__ __launch_bounds__(256) void router_k(const _Float16* __restrict__ x2h, const _Float16* __restrict__ x2l,
    const float* __restrict__ gw, const float* __restrict__ eb,
    int* __restrict__ cnt, int* __restrict__ list, float* __restrict__ wl, int* __restrict__ tokslot) {
  int t = blockIdx.x*4 + (threadIdx.x >> 6);
  int lane = threadIdx.x & 63;
  const _Float16* xh = x2h + (size_t)t*H_;
  const _Float16* xl = x2l + (size_t)t*H_;
  f32x4 a0 = {0,0,0,0}, a1 = {0,0,0,0}, a2 = {0,0,0,0}, a3 = {0,0,0,0};
  for (int h = lane; h < H_; h += 64) {
    float xv = (float)xh[h] + (float)xl[h] * LO_I;
    const float* g = gw + (size_t)h*16;
    a0 += xv * (*(const f32x4*)(g));
    a1 += xv * (*(const f32x4*)(g+4));
    a2 += xv * (*(const f32x4*)(g+8));
    a3 += xv * (*(const f32x4*)(g+12));
  }
  float acc[16];
  #pragma unroll
  for (int j = 0; j < 4; ++j) { acc[j]=a0[j]; acc[4+j]=a1[j]; acc[8+j]=a2[j]; acc[12+j]=a3[j]; }
  #pragma unroll
  for (int mm = 1; mm < 64; mm <<= 1) {
    #pragma unroll
    for (int e2 = 0; e2 < 16; ++e2) acc[e2] += __shfl_xor(acc[e2], mm);
  }
  if (lane == 0) {
    float sig[16], biased[16];
    #pragma unroll
    for (int e2 = 0; e2 < 16; ++e2) {
      float s = 1.0f / (1.0f + expf(-acc[e2]));
      sig[e2] = s; biased[e2] = s + eb[e2];
    }
    int sel[4]; float wv[4]; float wsum = 0.f;
    unsigned used = 0;
    for (int j = 0; j < 4; ++j) {
      int bi = -1; float bv = -1e30f;
      for (int e2 = 0; e2 < 16; ++e2)
        if (!((used >> e2) & 1) && biased[e2] > bv) { bv = biased[e2]; bi = e2; }
      used |= 1u << bi;
      sel[j] = bi; wv[j] = sig[bi]; wsum += sig[bi];
    }
    for (int j = 0; j < 4; ++j) {
      int e2 = sel[j];
      int pos = atomicAdd(&cnt[e2], 1);
      list[e2*T_ + pos] = t;
      wl[e2*T_ + pos] = wv[j] / wsum;
      tokslot[t*4 + j] = e2*T_ + pos;     // e = slot>>11, pos = slot&2047
    }
  }
}

__global__ void scan_k(const int* __restrict__ cnt, int* __restrict__ base) {
  if (threadIdx.x == 0 && blockIdx.x == 0) {
    int s = 0;
    for (int e2 = 0; e2 < 16; ++e2) { base[e2] = s; s += cnt[e2]; }
  }
}

// ---------------- combine: out[t] += sum_j eout[base[e_j]+pos_j]  (replaces 16.7M atomics) ----------------
__global__ __launch_bounds__(256) void combine_k(const int* __restrict__ tokslot, const int* __restrict__ base,
                                                 const float* __restrict__ eout, float* __restrict__ outp) {
  const int t = blockIdx.x, tid = threadIdx.x;
  const int col = tid * 8;
  int r[4];
  #pragma unroll
  for (int j = 0; j < 4; ++j) {
    int s = tokslot[t*4 + j];
    r[j] = base[s >> 11] + (s & 2047);
  }
  float* op = outp + (size_t)t*H_ + col;
  f32x4 a0 = *(const f32x4*)(op);
  f32x4 a1 = *(const f32x4*)(op + 4);
  #pragma unroll
  for (int j = 0; j < 4; ++j) {
    const float* er = eout + (size_t)r[j]*H_ + col;
    a0 += *(const f32x4*)(er);
    a1 += *(const f32x4*)(er + 4);
  }
  *(f32x4*)(op)     = a0;
  *(f32x4*)(op + 4) = a1;
}

// ---------------- GEMM args ----------------
struct GArgs {
  const _Float16* Ah; const _Float16* Al;
  const _Float16* Bh; const _Float16* Bl;
  int M, N, K;
  const int* rowlist; const float* wlist; const int* cnt; const int* base;
  float* C; const float* res; _Float16* act; float* outAt; int ldc;
};

// ---------------- 128x128 GEMM: 512 threads (8 waves, 2x4), counted-vmcnt pipeline ----------------
template<int MODE, bool SPLIT, int DEPTH>
__global__ __launch_bounds__(512, 4) void gemm_k(GArgs p) {
  constexpr int LPS = SPLIT ? 4 : 2;   // loads per stage per thread (1 per tensor)
  const int e = blockIdx.z;
  const int M = p.cnt ? p.cnt[e] : p.M;
  const int m0 = blockIdx.y * 128;
  if (m0 >= M) return;
  const int n0 = blockIdx.x * 128;
  const int tid = threadIdx.x;
  const int wid = tid >> 6, lane = tid & 63;

  __shared__ _Float16 sA[DEPTH][4096];
  __shared__ _Float16 sB[DEPTH][4096];
  __shared__ _Float16 sAl[SPLIT ? DEPTH : 1][SPLIT ? 4096 : 8];
  __shared__ _Float16 sBl[SPLIT ? DEPTH : 1][SPLIT ? 4096 : 8];

  const int srow = tid >> 2;
  const int slot = ((tid & 3) ^ (srow & 3)) * 16;
  const int ldsOff = wid * 1024;
  size_t aIdx;
  if constexpr (MODE == 2) {
    if (p.rowlist) {
      int tok = p.rowlist[(size_t)e * T_ + m0 + srow];
      tok = tok < 0 ? 0 : (tok > T_ - 1 ? T_ - 1 : tok);
      aIdx = (size_t)tok;
    } else aIdx = (size_t)(m0 + srow);
  } else if constexpr (MODE == 3) {
    aIdx = (size_t)p.base[e] + m0 + srow;
  } else {
    aIdx = (size_t)(m0 + srow);
  }
  const char* aPtr  = (const char*)(p.Ah + aIdx * (size_t)p.K) + slot;
  const char* alPtr = SPLIT ? (const char*)(p.Al + aIdx * (size_t)p.K) + slot : aPtr;
  const size_t bIdx = (size_t)e * p.N + n0 + srow;
  const char* bPtr  = (const char*)(p.Bh + bIdx * (size_t)p.K) + slot;
  const char* blPtr = SPLIT ? (const char*)(p.Bl + bIdx * (size_t)p.K) + slot : bPtr;

  auto stage = [&](int buf, int kb) {
    GL16(aPtr + kb, (char*)&sA[buf][0] + ldsOff);
    GL16(bPtr + kb, (char*)&sB[buf][0] + ldsOff);
    if constexpr (SPLIT) {
      GL16(alPtr + kb, (char*)&sAl[buf][0] + ldsOff);
      GL16(blPtr + kb, (char*)&sBl[buf][0] + ldsOff);
    }
  };

  const int wr = (wid >> 2) * 64, wc = (wid & 3) * 32;
  const int fr = lane & 15, fs = lane >> 4;

  f32x4 acc[4][2] = {};
  f32x4 acc2[4][2] = {};

  const int nt = p.K >> 5;
  stage(0, 0);
  if constexpr (DEPTH == 3) { if (nt > 1) stage(1, 64); }

  for (int t = 0; t < nt; ++t) {
    if constexpr (DEPTH == 3) {
      if (t + 2 < nt) stage((t + 2) % 3, (t + 2) * 64);
      __builtin_amdgcn_sched_barrier(0);
      if (t + 2 < nt)      asm volatile("s_waitcnt vmcnt(%0)" :: "i"(2*LPS) : "memory");
      else if (t + 1 < nt) asm volatile("s_waitcnt vmcnt(%0)" :: "i"(LPS)   : "memory");
      else                 asm volatile("s_waitcnt vmcnt(0)" ::: "memory");
    } else {
      if (t + 1 < nt) {
        stage((t + 1) & 1, (t + 1) * 64);
        __builtin_amdgcn_sched_barrier(0);
        asm volatile("s_waitcnt vmcnt(%0)" :: "i"(LPS) : "memory");
      } else {
        __builtin_amdgcn_sched_barrier(0);
        asm volatile("s_waitcnt vmcnt(0)" ::: "memory");
      }
    }
    __builtin_amdgcn_s_barrier();
    __builtin_amdgcn_sched_barrier(0);

    const int cb = (DEPTH == 3) ? (t % 3) : (t & 1);
    half8 ah[4], bh[2], al[4], bl[2];
    #pragma unroll
    for (int i = 0; i < 4; ++i) {
      const int pa = (fs ^ ((wr + i*16 + fr) & 3)) * 8;
      ah[i] = *(const half8*)&sA[cb][(wr + i*16 + fr)*32 + pa];
      if constexpr (SPLIT) al[i] = *(const half8*)&sAl[cb][(wr + i*16 + fr)*32 + pa];
    }
    #pragma unroll
    for (int i = 0; i < 2; ++i) {
      const int pb = (fs ^ ((wc + i*16 + fr) & 3)) * 8;
      bh[i] = *(const half8*)&sB[cb][(wc + i*16 + fr)*32 + pb];
      if constexpr (SPLIT) bl[i] = *(const half8*)&sBl[cb][(wc + i*16 + fr)*32 + pb];
    }
    __builtin_amdgcn_s_setprio(1);
    #pragma unroll
    for (int mi = 0; mi < 4; ++mi) {
      #pragma unroll
      for (int ni = 0; ni < 2; ++ni) {
        acc[mi][ni] = MFMA32(ah[mi], bh[ni], acc[mi][ni]);
        if constexpr (SPLIT) {
          acc2[mi][ni] = MFMA32(ah[mi], bl[ni], acc2[mi][ni]);
          acc2[mi][ni] = MFMA32(al[mi], bh[ni], acc2[mi][ni]);
        }
      }
    }
    __builtin_amdgcn_s_setprio(0);
    __builtin_amdgcn_sched_barrier(0);
    __builtin_amdgcn_s_barrier();
    __builtin_amdgcn_sched_barrier(0);
  }

  const int actld = p.N >> 1;
  #pragma unroll
  for (int mi = 0; mi < 4; ++mi) {
    #pragma unroll
    for (int ni = 0; ni < 2; ++ni) {
      f32x4 v4 = acc[mi][ni];
      if constexpr (SPLIT) v4 = v4 + acc2[mi][ni] * LO_I;
      const int colb = n0 + wc + ni*16 + fr;
      #pragma unroll
      for (int r = 0; r < 4; ++r) {
        const int row = m0 + wr + mi*16 + fs*4 + r;
        float val = v4[r];
        if constexpr (MODE == 0) {
          if (row < M) p.C[(size_t)row * p.ldc + colb] = val;
        } else if constexpr (MODE == 1) {
          if (row < M) p.C[(size_t)row * p.ldc + colb] = p.res[(size_t)row * p.ldc + colb] + val;
        } else if constexpr (MODE == 2) {
          float other = __shfl_xor(val, 1);
          float g = (fr & 1) ? other : val;
          float u = (fr & 1) ? val : other;
          float a = g / (1.0f + __expf(-g)) * u;
          if (!(fr & 1) && row < M) {
            size_t ar = (size_t)(p.base ? p.base[e] : 0) + row;
            p.act[ar * (size_t)actld + (colb >> 1)] = (_Float16)a;
          }
        } else {
          if (row < M) {
            float w = p.wlist[(size_t)e * T_ + row];
            p.outAt[((size_t)p.base[e] + row) * p.ldc + colb] = val * w;   // plain store (no atomics)
          }
        }
      }
    }
  }
}

// ---------------- launcher ----------------
extern "C" void kernel_launch(void* const* d_in, const int* in_sizes, int n_in,
                              void* d_out, int out_size, void* d_ws, size_t ws_size,
                              hipStream_t stream) {
  (void)in_sizes; (void)n_in; (void)out_size; (void)ws_size;
  const int*   positions = (const int*)  d_in[0];
  const float* hidden    = (const float*)d_in[1];
  const float* qkv_w     = (const float*)d_in[2];
  const float* o_w       = (const float*)d_in[3];
  const float* q_norm_w  = (const float*)d_in[4];
  const float* k_norm_w  = (const float*)d_in[5];
  const float* ln1_w     = (const float*)d_in[6];
  const float* ln2_w     = (const float*)d_in[7];
  const float* gate_w    = (const float*)d_in[8];
  const float* ebias     = (const float*)d_in[9];
  const float* sgu_w     = (const float*)d_in[10];
  const float* sdown_w   = (const float*)d_in[11];
  const float* egu_w     = (const float*)d_in[12];
  const float* edown_w   = (const float*)d_in[13];
  float* out = (float*)d_out;

  char* wsp = (char*)d_ws;
  size_t off = 0;
  auto alloc = [&](size_t bytes) -> void* {
    void* p = wsp + off;
    off = (off + bytes + 255) & ~(size_t)255;
    return p;
  };
  float*    cosT   = (float*)   alloc((size_t)T_*64*4);
  float*    sinT   = (float*)   alloc((size_t)T_*64*4);
  _Float16* x_h    = (_Float16*)alloc((size_t)T_*H_*2);
  _Float16* x_l    = (_Float16*)alloc((size_t)T_*H_*2);
  float*    qkvb   = (float*)   alloc((size_t)T_*4096*4);
  _Float16* q_h    = (_Float16*)alloc((size_t)NH_*T_*D_*2);
  _Float16* q_l    = (_Float16*)alloc((size_t)NH_*T_*D_*2);
  _Float16* k_h    = (_Float16*)alloc((size_t)NKV_*T_*D_*2);
  _Float16* k_l    = (_Float16*)alloc((size_t)NKV_*T_*D_*2);
  _Float16* vt_h   = (_Float16*)alloc((size_t)NKV_*T_*D_*2);
  _Float16* vt_l   = (_Float16*)alloc((size_t)NKV_*T_*D_*2);
  _Float16* ao_h   = (_Float16*)alloc((size_t)T_*NH_*D_*2);
  _Float16* ao_l   = (_Float16*)alloc((size_t)T_*NH_*D_*2);
  float*    hbuf   = (float*)   alloc((size_t)T_*H_*4);
  _Float16* x2_h   = (_Float16*)alloc((size_t)T_*H_*2);
  _Float16* x2_l   = (_Float16*)alloc((size_t)T_*H_*2);
  _Float16* qkvwT_h= (_Float16*)alloc((size_t)4096*H_*2);
  _Float16* qkvwT_l= (_Float16*)alloc((size_t)4096*H_*2);
  _Float16* owT_h  = (_Float16*)alloc((size_t)H_*H_*2);
  _Float16* owT_l  = (_Float16*)alloc((size_t)H_*H_*2);
  _Float16* sguT   = (_Float16*)alloc((size_t)2*SI_*H_*2);
  _Float16* sdownT = (_Float16*)alloc((size_t)H_*SI_*2);
  _Float16* eguT   = (_Float16*)alloc((size_t)E_*2*I_*H_*2);
  _Float16* edownT = (_Float16*)alloc((size_t)E_*H_*I_*2);
  _Float16* act_s  = (_Float16*)alloc((size_t)T_*SI_*2);
  _Float16* act_e  = (_Float16*)alloc((size_t)(T_*4 + 512)*I_*2);
  int*   cnt     = (int*)  alloc(E_*4);
  int*   ebase   = (int*)  alloc(E_*4);
  int*   list    = (int*)  alloc((size_t)E_*T_*4);
  float* wlst    = (float*)alloc((size_t)E_*T_*4);
  int*   tokslot = (int*)  alloc((size_t)T_*4*4);
  // expert-output buffer (8192 x H fp32 = 64 MiB) aliased onto dead-by-then
  // region [qkvb .. vt_l] (dead after qkvpost/attn; edown+combine run last).
  float* eout = qkvb;

  hipMemsetAsync(cnt, 0, E_*4, stream);
  tables_k<<<T_, 64, 0, stream>>>(positions, cosT, sinT);

  transpose_k<true ><<<dim3(4096/64, H_/64, 1), 256, 0, stream>>>(qkv_w, qkvwT_h, qkvwT_l, H_, 4096);
  transpose_k<true ><<<dim3(H_/64,  H_/64, 1), 256, 0, stream>>>(o_w, owT_h, owT_l, H_, H_);
  transpose_gu_k    <<<dim3(SI_/32, H_/64, 1), 256, 0, stream>>>(sgu_w, sguT, H_, SI_);
  transpose_k<false><<<dim3(H_/64, SI_/64, 1), 256, 0, stream>>>(sdown_w, sdownT, nullptr, SI_, H_);
  transpose_gu_k    <<<dim3(I_/32,  H_/64, E_), 256, 0, stream>>>(egu_w, eguT, H_, I_);
  transpose_k<false><<<dim3(H_/64,  I_/64, E_), 256, 0, stream>>>(edown_w, edownT, nullptr, I_, H_);

  rmsnorm_k<<<T_, 256, 0, stream>>>(hidden, ln1_w, x_h, x_l);

  { GArgs g{}; g.Ah=x_h; g.Al=x_l; g.Bh=qkvwT_h; g.Bl=qkvwT_l; g.M=T_; g.N=4096; g.K=H_;
    g.C=qkvb; g.ldc=4096;
    gemm_k<0,true,2><<<dim3(4096/128, T_/128, 1), 512, 0, stream>>>(g); }

  qkvpost_k<<<T_, 256, 0, stream>>>(qkvb, q_norm_w, k_norm_w, cosT, sinT,
                                    q_h, q_l, k_h, k_l, vt_h, vt_l);

  attn_k<<<dim3(NH_, 32), 256, 0, stream>>>(q_h, q_l, k_h, k_l, vt_h, vt_l, ao_h, ao_l);

  { GArgs g{}; g.Ah=ao_h; g.Al=ao_l; g.Bh=owT_h; g.Bl=owT_l; g.M=T_; g.N=H_; g.K=H_;
    g.C=hbuf; g.res=hidden; g.ldc=H_;
    gemm_k<1,true,2><<<dim3(H_/128, T_/128, 1), 512, 0, stream>>>(g); }

  rmsnorm_k<<<T_, 256, 0, stream>>>(hbuf, ln2_w, x2_h, x2_l);

  router_k<<<T_/4, 256, 0, stream>>>(x2_h, x2_l, gate_w, ebias, cnt, list, wlst, tokslot);
  scan_k<<<1, 64, 0, stream>>>(cnt, ebase);

  { GArgs g{}; g.Ah=x2_h; g.Bh=sguT; g.M=T_; g.N=2*SI_; g.K=H_; g.act=act_s;
    gemm_k<2,false,3><<<dim3(2*SI_/128, T_/128, 1), 512, 0, stream>>>(g); }

  { GArgs g{}; g.Ah=act_s; g.Bh=sdownT; g.M=T_; g.N=H_; g.K=SI_;
    g.C=out; g.res=hbuf; g.ldc=H_;
    gemm_k<1,false,3><<<dim3(H_/128, T_/128, 1), 512, 0, stream>>>(g); }

  { GArgs g{}; g.Ah=x2_h; g.Bh=eguT; g.M=T_; g.N=2*I_; g.K=H_;
    g.rowlist=list; g.cnt=cnt; g.base=ebase; g.act=act_e;
    gemm_k<2,false,3><<<dim3(2*I_/128, T_/128, E_), 512, 0, stream>>>(g); }

  { GArgs g{}; g.Ah=act_e; g.Bh=edownT; g.M=T_; g.N=H_; g.K=I_;
    g.wlist=wlst; g.cnt=cnt; g.base=ebase;
    g.outAt=eout; g.ldc=H_;
    gemm_k<3,false,3><<<dim3(H_/128, T_/128, E_), 512, 0, stream>>>(g); }

  combine_k<<<T_, 256, 0, stream>>>(tokslot, ebase, eout, out);
}